// Round 1
// baseline (1241.187 us; speedup 1.0000x reference)
//
#include <hip/hip_runtime.h>
#include <math.h>

#define BB 8
#define CC 128
#define CHID 64
#define HH 160
#define WW 160
#define HWP (HH*WW)

__device__ __forceinline__ float sgm(float z){ return 1.0f/(1.0f + __expf(-z)); }
__device__ __forceinline__ float silu_(float z){ return z/(1.0f + __expf(-z)); }

// clipped 3x3 window max/min (== maxpool3(x), -maxpool3(-x) with -inf SAME pad)
__device__ __forceinline__ void win3(const float* __restrict__ pl, int h, int w,
                                     float& mx, float& mn){
  int h0 = h>0 ? h-1 : 0, h1 = h<HH-1 ? h+1 : h;
  int w0 = w>0 ? w-1 : 0, w1 = w<WW-1 ? w+1 : w;
  float vmx = -INFINITY, vmn = INFINITY;
  for(int hh=h0; hh<=h1; ++hh){
    const float* r = pl + hh*WW;
    for(int ww=w0; ww<=w1; ++ww){ float v = r[ww]; vmx = fmaxf(vmx,v); vmn = fminf(vmn,v); }
  }
  mx = vmx; mn = vmn;
}

// K1: per (b,c) plane -> baseline(min of x), thr = 0.3*(mean(local_contrast)+1e-6)
__global__ __launch_bounds__(256) void k1_stats(const float* __restrict__ x,
                                                float* __restrict__ baseline,
                                                float* __restrict__ thr){
  int bc = blockIdx.x;
  const float* xp = x + (size_t)bc*HWP;
  float mn = INFINITY, sum = 0.f;
  for(int i=threadIdx.x; i<HWP; i+=256){
    int h = i/WW, w = i - h*WW;
    float wmx, wmn; win3(xp, h, w, wmx, wmn);
    sum += (wmx - wmn);
    mn = fminf(mn, xp[i]);
  }
  __shared__ float smn[256], ssm[256];
  smn[threadIdx.x]=mn; ssm[threadIdx.x]=sum; __syncthreads();
  for(int s=128; s>0; s>>=1){
    if(threadIdx.x < s){
      smn[threadIdx.x] = fminf(smn[threadIdx.x], smn[threadIdx.x+s]);
      ssm[threadIdx.x] += ssm[threadIdx.x+s];
    }
    __syncthreads();
  }
  if(threadIdx.x==0){
    baseline[bc] = smn[0];
    thr[bc] = 0.3f*(ssm[0]/(float)HWP + 1e-6f);
  }
}

// K2: filled = blend(x, baseline) by bg mask; write filled; per-(b,c) |filled| max/mean -> ch_weight
__global__ __launch_bounds__(256) void k2_fill(const float* __restrict__ x,
                                               const float* __restrict__ fsr,
                                               const float* __restrict__ baseline,
                                               const float* __restrict__ thr,
                                               float* __restrict__ filled,
                                               float* __restrict__ chw){
  int bc = blockIdx.x;
  int c = bc % CC;
  const float* xp = x + (size_t)bc*HWP;
  float* fp = filled + (size_t)bc*HWP;
  float s = sgm(fsr[c]);
  float base = baseline[bc], th = thr[bc];
  float amax = 0.f, asum = 0.f;
  for(int i=threadIdx.x; i<HWP; i+=256){
    int h = i/WW, w = i - h*WW;
    float wmx, wmn; win3(xp, h, w, wmx, wmn);
    float xv = xp[i];
    float f = ((wmx - wmn) < th) ? (xv*(1.f - s) + base*s) : xv;
    fp[i] = f;
    float a = fabsf(f);
    amax = fmaxf(amax, a); asum += a;
  }
  __shared__ float smx[256], ssm[256];
  smx[threadIdx.x]=amax; ssm[threadIdx.x]=asum; __syncthreads();
  for(int st=128; st>0; st>>=1){
    if(threadIdx.x < st){
      smx[threadIdx.x] = fmaxf(smx[threadIdx.x], smx[threadIdx.x+st]);
      ssm[threadIdx.x] += ssm[threadIdx.x+st];
    }
    __syncthreads();
  }
  if(threadIdx.x==0){
    float mx = smx[0], av = ssm[0]/(float)HWP;
    chw[bc] = sgm(3.0f*(mx - av - 0.3f));
  }
}

// K3: x_spatial[b,p] = mean_c |filled|
__global__ __launch_bounds__(256) void k3_xs(const float* __restrict__ filled,
                                             float* __restrict__ xs){
  int i = blockIdx.x*256 + threadIdx.x;       // < BB*HWP
  int b = i / HWP; int p = i - b*HWP;
  const float* fp = filled + (size_t)b*CC*HWP + p;
  float sum = 0.f;
  #pragma unroll 4
  for(int c=0; c<CC; ++c) sum += fabsf(fp[(size_t)c*HWP]);
  xs[i] = sum * (1.0f/(float)CC);
}

// K4: edge_weight[b,p] = sigmoid(5*((win3max-win3min)(xs) - 0.5))
__global__ __launch_bounds__(256) void k4_ew(const float* __restrict__ xs,
                                             float* __restrict__ ew){
  int i = blockIdx.x*256 + threadIdx.x;
  int b = i / HWP; int p = i - b*HWP;
  int h = p/WW, w = p - h*WW;
  float mx, mn; win3(xs + (size_t)b*HWP, h, w, mx, mn);
  ew[i] = sgm(5.0f*((mx - mn) - 0.5f));
}

// K5: o1 = silu(bn1(conv1x1(enhanced, w1))); enhanced folded: (1+ew[p]) * sum_ic (w1[oc,ic]*chw[ic]) * filled
__global__ __launch_bounds__(256) void k5_conv1(const float* __restrict__ filled,
                                                const float* __restrict__ chw,
                                                const float* __restrict__ ew,
                                                const float* __restrict__ w1,
                                                const float* __restrict__ g1,
                                                const float* __restrict__ b1,
                                                const float* __restrict__ m1,
                                                const float* __restrict__ v1,
                                                float* __restrict__ o1){
  __shared__ float wl[CC][CHID];   // [ic][oc], chw-folded
  __shared__ float al[CC][64];     // [ic][pix]
  int b  = blockIdx.x / 400;
  int p0 = (blockIdx.x % 400) * 64;
  int tid = threadIdx.x;
  for(int e=tid; e<CC*CHID; e+=256){
    int ic = e >> 6, oc = e & 63;
    wl[ic][oc] = w1[oc*CC + ic] * chw[b*CC + ic];
  }
  for(int e=tid; e<CC*64; e+=256){
    int ic = e >> 6, p = e & 63;
    al[ic][p] = filled[((size_t)(b*CC + ic))*HWP + p0 + p];
  }
  __syncthreads();
  int pg = tid & 15, og = tid >> 4;      // 4 pixels, 4 ocs per thread
  float acc[4][4] = {{0.f}};
  #pragma unroll 4
  for(int ic=0; ic<CC; ++ic){
    float4 a = *(const float4*)&al[ic][pg*4];
    float4 wv = *(const float4*)&wl[ic][og*4];
    float av[4] = {a.x,a.y,a.z,a.w};
    float wf[4] = {wv.x,wv.y,wv.z,wv.w};
    #pragma unroll
    for(int o=0;o<4;++o)
      #pragma unroll
      for(int j=0;j<4;++j) acc[o][j] += wf[o]*av[j];
  }
  float4 e4 = *(const float4*)&ew[b*HWP + p0 + pg*4];
  float ewf[4] = {1.f+e4.x, 1.f+e4.y, 1.f+e4.z, 1.f+e4.w};
  #pragma unroll
  for(int o=0;o<4;++o){
    int oc = og*4 + o;
    float sc = g1[oc]*rsqrtf(v1[oc] + 1e-5f);
    float sh = b1[oc] - m1[oc]*sc;
    float4 r;
    float* rr = (float*)&r;
    #pragma unroll
    for(int j=0;j<4;++j){
      float z = acc[o][j]*ewf[j]*sc + sh;
      rr[j] = silu_(z);
    }
    *(float4*)&o1[((size_t)(b*CHID + oc))*HWP + p0 + pg*4] = r;
  }
}

// K6: o2 = silu(bn2(conv3x3(o1, w2))), zero-pad SAME. 16x16 tile per block.
__global__ __launch_bounds__(256) void k6_conv2(const float* __restrict__ o1,
                                                const float* __restrict__ w2,
                                                const float* __restrict__ g2,
                                                const float* __restrict__ b2,
                                                const float* __restrict__ m2,
                                                const float* __restrict__ v2,
                                                float* __restrict__ o2){
  __shared__ float inl[16*18*18];      // [ic][18][18]
  __shared__ float wl[16*CHID*9];      // [ic][oc][9]
  int b  = blockIdx.x / 100;
  int t  = blockIdx.x % 100;
  int gh0 = (t/10)*16, gw0 = (t%10)*16;
  int tid = threadIdx.x;
  int og = tid >> 6;            // 0..3 -> 16 ocs
  int pg = tid & 63;            // 64 pixel groups of 4
  int r  = pg >> 2;             // row 0..15
  int c4 = (pg & 3)*4;          // col 0,4,8,12
  int ocb = og*16;
  float acc[16][4] = {{0.f}};
  for(int ic0=0; ic0<CHID; ic0+=16){
    if(ic0) __syncthreads();
    for(int e=tid; e<16*324; e+=256){
      int ic = e/324; int rem = e - ic*324;
      int rr = rem/18; int cc2 = rem - rr*18;
      int gh = gh0 - 1 + rr, gw = gw0 - 1 + cc2;
      float v = 0.f;
      if(gh>=0 && gh<HH && gw>=0 && gw<WW)
        v = o1[((size_t)(b*CHID + ic0 + ic))*HWP + gh*WW + gw];
      inl[e] = v;
    }
    for(int e=tid; e<16*CHID*9; e+=256){
      int ic = e/576; int rem = e - ic*576;
      int oc = rem/9; int k = rem - oc*9;
      wl[e] = w2[((size_t)oc*CHID + ic0 + ic)*9 + k];
    }
    __syncthreads();
    for(int ic=0; ic<16; ++ic){
      float iv[3][6];
      #pragma unroll
      for(int dr=0; dr<3; ++dr)
        #pragma unroll
        for(int dc=0; dc<6; ++dc)
          iv[dr][dc] = inl[ic*324 + (r+dr)*18 + (c4+dc)];
      #pragma unroll
      for(int o=0; o<16; ++o){
        const float* wp = &wl[(ic*CHID + ocb + o)*9];
        float wv[9];
        #pragma unroll
        for(int k=0;k<9;++k) wv[k] = wp[k];
        #pragma unroll
        for(int j=0;j<4;++j){
          acc[o][j] += wv[0]*iv[0][j] + wv[1]*iv[0][j+1] + wv[2]*iv[0][j+2]
                     + wv[3]*iv[1][j] + wv[4]*iv[1][j+1] + wv[5]*iv[1][j+2]
                     + wv[6]*iv[2][j] + wv[7]*iv[2][j+1] + wv[8]*iv[2][j+2];
        }
      }
    }
  }
  #pragma unroll
  for(int o=0; o<16; ++o){
    int oc = ocb + o;
    float sc = g2[oc]*rsqrtf(v2[oc] + 1e-5f);
    float sh = b2[oc] - m2[oc]*sc;
    float4 rv;
    float* rr2 = (float*)&rv;
    #pragma unroll
    for(int j=0;j<4;++j){
      float z = acc[o][j]*sc + sh;
      rr2[j] = silu_(z);
    }
    *(float4*)&o2[((size_t)(b*CHID + oc))*HWP + (gh0+r)*WW + gw0 + c4] = rv;
  }
}

// K7: out = silu(bn3(conv1x1(o2, w3)) + enhanced)
__global__ __launch_bounds__(256) void k7_conv3(const float* __restrict__ o2,
                                                const float* __restrict__ w3,
                                                const float* __restrict__ g3,
                                                const float* __restrict__ b3,
                                                const float* __restrict__ m3,
                                                const float* __restrict__ v3,
                                                const float* __restrict__ filled,
                                                const float* __restrict__ chw,
                                                const float* __restrict__ ew,
                                                float* __restrict__ out){
  __shared__ float wl[CHID][CC];   // [ic][oc]
  __shared__ float al[CHID][64];   // [ic][pix]
  int b  = blockIdx.x / 400;
  int p0 = (blockIdx.x % 400) * 64;
  int tid = threadIdx.x;
  for(int e=tid; e<CHID*CC; e+=256){
    int ic = e >> 7, oc = e & 127;
    wl[ic][oc] = w3[oc*CHID + ic];
  }
  for(int e=tid; e<CHID*64; e+=256){
    int ic = e >> 6, p = e & 63;
    al[ic][p] = o2[((size_t)(b*CHID + ic))*HWP + p0 + p];
  }
  __syncthreads();
  int pg = tid & 15, og = tid >> 4;   // 4 pixels, 8 ocs per thread
  float acc[8][4] = {{0.f}};
  #pragma unroll 4
  for(int ic=0; ic<CHID; ++ic){
    float4 a  = *(const float4*)&al[ic][pg*4];
    float4 wa = *(const float4*)&wl[ic][og*8];
    float4 wb = *(const float4*)&wl[ic][og*8+4];
    float av[4] = {a.x,a.y,a.z,a.w};
    float wf[8] = {wa.x,wa.y,wa.z,wa.w, wb.x,wb.y,wb.z,wb.w};
    #pragma unroll
    for(int o=0;o<8;++o)
      #pragma unroll
      for(int j=0;j<4;++j) acc[o][j] += wf[o]*av[j];
  }
  float4 e4 = *(const float4*)&ew[b*HWP + p0 + pg*4];
  float ewf[4] = {1.f+e4.x, 1.f+e4.y, 1.f+e4.z, 1.f+e4.w};
  #pragma unroll
  for(int o=0;o<8;++o){
    int oc = og*8 + o;
    float sc = g3[oc]*rsqrtf(v3[oc] + 1e-5f);
    float sh = b3[oc] - m3[oc]*sc;
    float cw = chw[b*CC + oc];
    float4 f4 = *(const float4*)&filled[((size_t)(b*CC + oc))*HWP + p0 + pg*4];
    float fv[4] = {f4.x,f4.y,f4.z,f4.w};
    float4 rv;
    float* rr = (float*)&rv;
    #pragma unroll
    for(int j=0;j<4;++j){
      float enh = fv[j]*cw*ewf[j];
      float z = acc[o][j]*sc + sh + enh;
      rr[j] = silu_(z);
    }
    *(float4*)&out[((size_t)(b*CC + oc))*HWP + p0 + pg*4] = rv;
  }
}

extern "C" void kernel_launch(void* const* d_in, const int* in_sizes, int n_in,
                              void* d_out, int out_size, void* d_ws, size_t ws_size,
                              hipStream_t stream) {
  const float* x   = (const float*)d_in[0];
  const float* fsr = (const float*)d_in[1];
  const float* w1  = (const float*)d_in[2];
  const float* g1  = (const float*)d_in[3];
  const float* b1  = (const float*)d_in[4];
  const float* m1  = (const float*)d_in[5];
  const float* v1  = (const float*)d_in[6];
  const float* w2  = (const float*)d_in[7];
  const float* g2  = (const float*)d_in[8];
  const float* b2  = (const float*)d_in[9];
  const float* m2  = (const float*)d_in[10];
  const float* v2  = (const float*)d_in[11];
  const float* w3  = (const float*)d_in[12];
  const float* g3  = (const float*)d_in[13];
  const float* b3  = (const float*)d_in[14];
  const float* m3  = (const float*)d_in[15];
  const float* v3  = (const float*)d_in[16];
  float* out = (float*)d_out;

  float* ws = (float*)d_ws;
  float* filled   = ws;                         // 26,214,400
  float* o1       = filled + (size_t)BB*CC*HWP; // 13,107,200
  float* o2       = o1 + (size_t)BB*CHID*HWP;   // 13,107,200
  float* xs       = o2 + (size_t)BB*CHID*HWP;   // 204,800
  float* ewb      = xs + (size_t)BB*HWP;        // 204,800
  float* baseline = ewb + (size_t)BB*HWP;       // 1024
  float* thr      = baseline + BB*CC;           // 1024
  float* chw      = thr + BB*CC;                // 1024

  k1_stats<<<dim3(BB*CC), dim3(256), 0, stream>>>(x, baseline, thr);
  k2_fill <<<dim3(BB*CC), dim3(256), 0, stream>>>(x, fsr, baseline, thr, filled, chw);
  k3_xs   <<<dim3(BB*HWP/256), dim3(256), 0, stream>>>(filled, xs);
  k4_ew   <<<dim3(BB*HWP/256), dim3(256), 0, stream>>>(xs, ewb);
  k5_conv1<<<dim3(BB*400), dim3(256), 0, stream>>>(filled, chw, ewb, w1, g1, b1, m1, v1, o1);
  k6_conv2<<<dim3(BB*100), dim3(256), 0, stream>>>(o1, w2, g2, b2, m2, v2, o2);
  k7_conv3<<<dim3(BB*400), dim3(256), 0, stream>>>(o2, w3, g3, b3, m3, v3, filled, chw, ewb, out);
}

// Round 2
// 653.427 us; speedup vs baseline: 1.8995x; 1.8995x over previous
//
#include <hip/hip_runtime.h>
#include <math.h>

#define BB 8
#define CC 128
#define CH 64
#define HH 160
#define WW 160
#define HW (HH*WW)
#define PP 162            // padded width/height for conv2 input
#define INF __builtin_inff()

typedef __bf16 bfv8 __attribute__((ext_vector_type(8)));
typedef __bf16 bfv4 __attribute__((ext_vector_type(4)));
typedef float  f4   __attribute__((ext_vector_type(4)));

__device__ __forceinline__ float sgm(float z){ return 1.0f/(1.0f + __expf(-z)); }
__device__ __forceinline__ float silu_(float z){ return z/(1.0f + __expf(-z)); }
__device__ __forceinline__ f4 MFMA(bfv8 a, bfv8 b, f4 c){
  return __builtin_amdgcn_mfma_f32_16x16x32_bf16(a, b, c, 0, 0, 0);
}

// row-wise clipped 3-point max/min at column w of row rp; returns center value
__device__ __forceinline__ float hrow3(const float* __restrict__ rp, int w,
                                       float& hM, float& hm){
  float c = rp[w];
  float M = c, m = c;
  if(w > 0){   float l = rp[w-1]; M = fmaxf(M,l); m = fminf(m,l); }
  if(w < WW-1){float r = rp[w+1]; M = fmaxf(M,r); m = fminf(m,r); }
  hM = M; hm = m;
  return c;
}

// K1: per (b,c) plane -> baseline(min x), thr = 0.3*(mean(local_contrast)+1e-6)
__global__ __launch_bounds__(256) void k1_stats(const float* __restrict__ x,
                                                float* __restrict__ baseline,
                                                float* __restrict__ thr){
  int bc = blockIdx.x;
  int w  = threadIdx.x;
  const float* xp = x + (size_t)bc*HW;
  float mn = INF, sum = 0.f;
  if(w < WW){
    float hMp=-INF, hmp=INF, hMc, hmc, hMn, hmn;
    mn = hrow3(xp, w, hMc, hmc);
    for(int h=0; h<HH; ++h){
      if(h < HH-1){ float cn = hrow3(xp + (h+1)*WW, w, hMn, hmn); mn = fminf(mn, cn); }
      else { hMn = -INF; hmn = INF; }
      sum += fmaxf(fmaxf(hMp,hMc),hMn) - fminf(fminf(hmp,hmc),hmn);
      hMp=hMc; hmp=hmc; hMc=hMn; hmc=hmn;
    }
  }
  __shared__ float smn[256], ssm[256];
  smn[threadIdx.x]=mn; ssm[threadIdx.x]=sum; __syncthreads();
  for(int s=128; s>0; s>>=1){
    if(threadIdx.x < s){
      smn[threadIdx.x] = fminf(smn[threadIdx.x], smn[threadIdx.x+s]);
      ssm[threadIdx.x] += ssm[threadIdx.x+s];
    }
    __syncthreads();
  }
  if(threadIdx.x==0){
    baseline[bc] = smn[0];
    thr[bc] = 0.3f*(ssm[0]/(float)HW + 1e-6f);
  }
}

// K2: filled = blend(x, baseline) by bg mask; per-(b,c) |filled| max/mean -> chw
__global__ __launch_bounds__(256) void k2_fill(const float* __restrict__ x,
                                               const float* __restrict__ fsr,
                                               const float* __restrict__ baseline,
                                               const float* __restrict__ thr,
                                               float* __restrict__ filled,
                                               float* __restrict__ chw){
  int bc = blockIdx.x;
  int c  = bc % CC;
  int w  = threadIdx.x;
  const float* xp = x + (size_t)bc*HW;
  float* fp = filled + (size_t)bc*HW;
  float s = sgm(fsr[c]);
  float base = baseline[bc], th = thr[bc];
  float amax = 0.f, asum = 0.f;
  if(w < WW){
    float hMp=-INF, hmp=INF, hMc, hmc, hMn, hmn;
    float cc = hrow3(xp, w, hMc, hmc);
    for(int h=0; h<HH; ++h){
      float cn = 0.f;
      if(h < HH-1){ cn = hrow3(xp + (h+1)*WW, w, hMn, hmn); }
      else { hMn = -INF; hmn = INF; }
      float contrast = fmaxf(fmaxf(hMp,hMc),hMn) - fminf(fminf(hmp,hmc),hmn);
      float f = (contrast < th) ? cc*(1.f-s) + base*s : cc;
      fp[h*WW + w] = f;
      float a = fabsf(f);
      amax = fmaxf(amax, a); asum += a;
      hMp=hMc; hmp=hmc; hMc=hMn; hmc=hmn; cc=cn;
    }
  }
  __shared__ float smx[256], ssm[256];
  smx[threadIdx.x]=amax; ssm[threadIdx.x]=asum; __syncthreads();
  for(int st=128; st>0; st>>=1){
    if(threadIdx.x < st){
      smx[threadIdx.x] = fmaxf(smx[threadIdx.x], smx[threadIdx.x+st]);
      ssm[threadIdx.x] += ssm[threadIdx.x+st];
    }
    __syncthreads();
  }
  if(threadIdx.x==0){
    chw[bc] = sgm(3.0f*(smx[0] - ssm[0]/(float)HW - 0.3f));
  }
}

// K3: xs[b,p] = mean_c |filled|, vectorized f4
__global__ __launch_bounds__(256) void k3_xs(const float* __restrict__ filled,
                                             float* __restrict__ xs){
  int i = blockIdx.x*256 + threadIdx.x;       // BB*HW/4 units
  int b = i / (HW/4); int p4 = (i - b*(HW/4))*4;
  const float* fp = filled + (size_t)b*CC*HW + p4;
  f4 s = {0.f,0.f,0.f,0.f};
  #pragma unroll 4
  for(int c=0; c<CC; ++c){
    f4 v = *(const f4*)(fp + (size_t)c*HW);
    s.x += fabsf(v.x); s.y += fabsf(v.y); s.z += fabsf(v.z); s.w += fabsf(v.w);
  }
  f4 r = {s.x*(1.f/CC), s.y*(1.f/CC), s.z*(1.f/CC), s.w*(1.f/CC)};
  *(f4*)(xs + (size_t)b*HW + p4) = r;
}

// K4: edge weight via rolling 3x3 contrast on xs; strips of 32 rows
__global__ __launch_bounds__(256) void k4_ew(const float* __restrict__ xs,
                                             float* __restrict__ ew){
  int b  = blockIdx.x / 5;
  int r0 = (blockIdx.x % 5) * 32;
  int w  = threadIdx.x;
  if(w >= WW) return;
  const float* xp = xs + (size_t)b*HW;
  float* ep = ew + (size_t)b*HW;
  float hMp, hmp, hMc, hmc, hMn, hmn;
  if(r0 > 0) hrow3(xp + (r0-1)*WW, w, hMp, hmp); else { hMp=-INF; hmp=INF; }
  hrow3(xp + r0*WW, w, hMc, hmc);
  for(int h=r0; h<r0+32; ++h){
    if(h < HH-1) hrow3(xp + (h+1)*WW, w, hMn, hmn); else { hMn=-INF; hmn=INF; }
    float contrast = fmaxf(fmaxf(hMp,hMc),hMn) - fminf(fminf(hmp,hmc),hmn);
    ep[h*WW + w] = sgm(5.0f*(contrast - 0.5f));
    hMp=hMc; hmp=hmc; hMc=hMn; hmc=hmn;
  }
}

// K5: enh[b][p][ic] (NHWC bf16) = filled * chw * (1+ew), via LDS transpose
__global__ __launch_bounds__(256) void k_enh(const float* __restrict__ filled,
                                             const float* __restrict__ chw,
                                             const float* __restrict__ ew,
                                             __bf16* __restrict__ enh){
  __shared__ __bf16 tile[64][132];
  int b  = blockIdx.x / 400;
  int p0 = (blockIdx.x % 400) * 64;
  int t  = threadIdx.x;
  #pragma unroll 4
  for(int e=0; e<32; ++e){
    int idx = e*256 + t; int ic = idx >> 6; int p = idx & 63;
    float v = filled[((size_t)(b*CC + ic))*HW + p0 + p];
    float g = chw[b*CC + ic] * (1.f + ew[(size_t)b*HW + p0 + p]);
    tile[p][ic] = (__bf16)(v * g);
  }
  __syncthreads();
  #pragma unroll
  for(int e=0; e<8; ++e){
    int idx = e*256 + t; int p = idx >> 5; int icg = idx & 31;
    bfv4 v = *(const bfv4*)&tile[p][icg*4];
    *(bfv4*)&enh[((size_t)(b*HW + p0 + p))*CC + icg*4] = v;
  }
}

// C1: o1p(padded NHWC bf16) = silu(bn1(w1 @ enh));  M=64, K=128, N=pixels
__global__ __launch_bounds__(256) void c1_mfma(const __bf16* __restrict__ enh,
                                               const float* __restrict__ w1,
                                               const float* __restrict__ g1,
                                               const float* __restrict__ b1,
                                               const float* __restrict__ m1,
                                               const float* __restrict__ v1,
                                               __bf16* __restrict__ o1p){
  int lane = threadIdx.x & 63, wv = threadIdx.x >> 6;
  int u = blockIdx.x*4 + wv;            // 2560 units: b(8) x h(160) x half(2)
  int b = u / 320; int r = u % 320; int h = r >> 1; int w0base = (r & 1)*80;
  int q = lane >> 4, j = lane & 15;
  bfv8 afr[4][4];
  #pragma unroll
  for(int mt=0; mt<4; ++mt){
    int oc = mt*16 + j;
    #pragma unroll
    for(int kk=0; kk<4; ++kk){
      const float* wp = w1 + oc*CC + kk*32 + q*8;
      bfv8 a;
      #pragma unroll
      for(int e=0; e<8; ++e) a[e] = (__bf16)wp[e];
      afr[mt][kk] = a;
    }
  }
  float sc[4][4], sh[4][4];
  #pragma unroll
  for(int mt=0; mt<4; ++mt)
    #pragma unroll
    for(int rr=0; rr<4; ++rr){
      int oc = mt*16 + q*4 + rr;
      float s = g1[oc]*rsqrtf(v1[oc] + 1e-5f);
      sc[mt][rr] = s; sh[mt][rr] = b1[oc] - m1[oc]*s;
    }
  const __bf16* ebase = enh + (size_t)b*HW*CC;
  __bf16* obase = o1p + (size_t)b*PP*PP*CH;
  for(int s5=0; s5<5; ++s5){
    int w0 = w0base + s5*16;
    int p0 = h*WW + w0;
    const __bf16* bp = ebase + (size_t)(p0 + j)*CC + q*8;
    bfv8 bf[4];
    #pragma unroll
    for(int kk=0; kk<4; ++kk) bf[kk] = *(const bfv8*)(bp + kk*32);
    f4 acc[4] = {{0,0,0,0},{0,0,0,0},{0,0,0,0},{0,0,0,0}};
    #pragma unroll
    for(int kk=0; kk<4; ++kk)
      #pragma unroll
      for(int mt=0; mt<4; ++mt)
        acc[mt] = MFMA(afr[mt][kk], bf[kk], acc[mt]);
    int w = w0 + j;
    __bf16* op = obase + ((size_t)(h+1)*PP + (w+1))*CH + q*4;
    #pragma unroll
    for(int mt=0; mt<4; ++mt){
      bfv4 ov;
      #pragma unroll
      for(int rr=0; rr<4; ++rr){
        float z = acc[mt][rr]*sc[mt][rr] + sh[mt][rr];
        ov[rr] = (__bf16)silu_(z);
      }
      *(bfv4*)(op + mt*16) = ov;
    }
  }
}

// C2: o2(NHWC bf16) = silu(bn2(conv3x3(o1p, w2))); 9 taps from padded buffer
__global__ __launch_bounds__(256) void c2_mfma(const __bf16* __restrict__ o1p,
                                               const float* __restrict__ w2,
                                               const float* __restrict__ g2,
                                               const float* __restrict__ b2,
                                               const float* __restrict__ m2,
                                               const float* __restrict__ v2,
                                               __bf16* __restrict__ o2){
  int lane = threadIdx.x & 63, mt = threadIdx.x >> 6;
  int b = blockIdx.x / HH, h = blockIdx.x % HH;
  int q = lane >> 4, j = lane & 15;
  int oc = mt*16 + j;
  bfv8 afr[9][2];
  #pragma unroll
  for(int t=0; t<9; ++t)
    #pragma unroll
    for(int icb=0; icb<2; ++icb){
      const float* wp = w2 + ((size_t)oc*CH + icb*32 + q*8)*9 + t;
      bfv8 a;
      #pragma unroll
      for(int e=0; e<8; ++e) a[e] = (__bf16)wp[e*9];
      afr[t][icb] = a;
    }
  float sc[4], sh[4];
  #pragma unroll
  for(int rr=0; rr<4; ++rr){
    int o = mt*16 + q*4 + rr;
    float s = g2[o]*rsqrtf(v2[o] + 1e-5f);
    sc[rr] = s; sh[rr] = b2[o] - m2[o]*s;
  }
  const __bf16* ibase = o1p + (size_t)b*PP*PP*CH;
  __bf16* obase = o2 + (size_t)b*HW*CH;
  for(int w0=0; w0<WW; w0+=16){
    f4 acc = {0.f,0.f,0.f,0.f};
    #pragma unroll
    for(int dh=0; dh<3; ++dh){
      const __bf16* rp = ibase + ((size_t)(h+dh)*PP + w0 + j)*CH + q*8;
      #pragma unroll
      for(int dw=0; dw<3; ++dw)
        #pragma unroll
        for(int icb=0; icb<2; ++icb){
          bfv8 bf = *(const bfv8*)(rp + dw*CH + icb*32);
          acc = MFMA(afr[dh*3+dw][icb], bf, acc);
        }
    }
    __bf16* op = obase + ((size_t)(h*WW + w0 + j))*CH + mt*16 + q*4;
    bfv4 ov;
    #pragma unroll
    for(int rr=0; rr<4; ++rr){
      float z = acc[rr]*sc[rr] + sh[rr];
      ov[rr] = (__bf16)silu_(z);
    }
    *(bfv4*)op = ov;
  }
}

// C3: out(NCHW f32) = silu(bn3(w3 @ o2) + filled*chw*(1+ew)); M=128, K=64
__global__ __launch_bounds__(256) void c3_mfma(const __bf16* __restrict__ o2,
                                               const float* __restrict__ w3,
                                               const float* __restrict__ g3,
                                               const float* __restrict__ b3,
                                               const float* __restrict__ m3,
                                               const float* __restrict__ v3,
                                               const float* __restrict__ filled,
                                               const float* __restrict__ chw,
                                               const float* __restrict__ ew,
                                               float* __restrict__ out){
  int lane = threadIdx.x & 63, wv = threadIdx.x >> 6;
  int u = blockIdx.x*4 + wv;            // 5120 units: b x h x seg(2) x ochalf(2)
  int b = u / 640; int r = u % 640; int h = r >> 2; int t = r & 3;
  int oh = t & 1; int w0base = (t >> 1)*80;
  int q = lane >> 4, j = lane & 15;
  bfv8 afr[4][2];
  #pragma unroll
  for(int mt=0; mt<4; ++mt){
    int oc = oh*64 + mt*16 + j;
    #pragma unroll
    for(int kk=0; kk<2; ++kk){
      const float* wp = w3 + oc*CH + kk*32 + q*8;
      bfv8 a;
      #pragma unroll
      for(int e=0; e<8; ++e) a[e] = (__bf16)wp[e];
      afr[mt][kk] = a;
    }
  }
  float sc[4][4], sh[4][4], cw[4][4];
  #pragma unroll
  for(int mt=0; mt<4; ++mt)
    #pragma unroll
    for(int rr=0; rr<4; ++rr){
      int oc = oh*64 + mt*16 + q*4 + rr;
      float s = g3[oc]*rsqrtf(v3[oc] + 1e-5f);
      sc[mt][rr] = s; sh[mt][rr] = b3[oc] - m3[oc]*s;
      cw[mt][rr] = chw[b*CC + oc];
    }
  const __bf16* ibase = o2 + (size_t)b*HW*CH;
  for(int s5=0; s5<5; ++s5){
    int w0 = w0base + s5*16;
    int p0 = h*WW + w0;
    int pix = p0 + j;
    const __bf16* bp = ibase + (size_t)pix*CH + q*8;
    bfv8 bf0 = *(const bfv8*)bp;
    bfv8 bf1 = *(const bfv8*)(bp + 32);
    f4 acc[4] = {{0,0,0,0},{0,0,0,0},{0,0,0,0},{0,0,0,0}};
    #pragma unroll
    for(int mt=0; mt<4; ++mt){
      acc[mt] = MFMA(afr[mt][0], bf0, acc[mt]);
      acc[mt] = MFMA(afr[mt][1], bf1, acc[mt]);
    }
    float ewv = 1.f + ew[(size_t)b*HW + pix];
    #pragma unroll
    for(int mt=0; mt<4; ++mt)
      #pragma unroll
      for(int rr=0; rr<4; ++rr){
        int oc = oh*64 + mt*16 + q*4 + rr;
        size_t gix = ((size_t)(b*CC + oc))*HW + pix;
        float res = filled[gix] * cw[mt][rr] * ewv;
        float z = acc[mt][rr]*sc[mt][rr] + sh[mt][rr] + res;
        out[gix] = silu_(z);
      }
  }
}

extern "C" void kernel_launch(void* const* d_in, const int* in_sizes, int n_in,
                              void* d_out, int out_size, void* d_ws, size_t ws_size,
                              hipStream_t stream) {
  const float* x   = (const float*)d_in[0];
  const float* fsr = (const float*)d_in[1];
  const float* w1  = (const float*)d_in[2];
  const float* g1  = (const float*)d_in[3];
  const float* b1  = (const float*)d_in[4];
  const float* m1  = (const float*)d_in[5];
  const float* v1  = (const float*)d_in[6];
  const float* w2  = (const float*)d_in[7];
  const float* g2  = (const float*)d_in[8];
  const float* b2  = (const float*)d_in[9];
  const float* m2  = (const float*)d_in[10];
  const float* v2  = (const float*)d_in[11];
  const float* w3  = (const float*)d_in[12];
  const float* g3  = (const float*)d_in[13];
  const float* b3  = (const float*)d_in[14];
  const float* m3  = (const float*)d_in[15];
  const float* v3  = (const float*)d_in[16];
  float* out = (float*)d_out;

  char* wp = (char*)d_ws;
  float*  filled = (float*)wp;   wp += (size_t)BB*CC*HW*4;       // 104.9 MB
  __bf16* enh    = (__bf16*)wp;  wp += (size_t)BB*HW*CC*2;       // 52.4 MB
  __bf16* o1p    = (__bf16*)wp;  wp += (size_t)BB*PP*PP*CH*2;    // 26.9 MB
  __bf16* o2b    = (__bf16*)wp;  wp += (size_t)BB*HW*CH*2;       // 26.2 MB
  float*  xs     = (float*)wp;   wp += (size_t)BB*HW*4;
  float*  ewb    = (float*)wp;   wp += (size_t)BB*HW*4;
  float*  baseline = (float*)wp; wp += 1024*4;
  float*  thr    = (float*)wp;   wp += 1024*4;
  float*  chw    = (float*)wp;   wp += 1024*4;

  // zero padded conv2 input (borders must be 0 every launch)
  hipMemsetAsync(o1p, 0, (size_t)BB*PP*PP*CH*2, stream);

  k1_stats<<<dim3(BB*CC), dim3(256), 0, stream>>>(x, baseline, thr);
  k2_fill <<<dim3(BB*CC), dim3(256), 0, stream>>>(x, fsr, baseline, thr, filled, chw);
  k3_xs   <<<dim3(BB*HW/4/256), dim3(256), 0, stream>>>(filled, xs);
  k4_ew   <<<dim3(BB*5), dim3(256), 0, stream>>>(xs, ewb);
  k_enh   <<<dim3(BB*400), dim3(256), 0, stream>>>(filled, chw, ewb, enh);
  c1_mfma <<<dim3(640), dim3(256), 0, stream>>>(enh, w1, g1, b1, m1, v1, o1p);
  c2_mfma <<<dim3(BB*HH), dim3(256), 0, stream>>>(o1p, w2, g2, b2, m2, v2, o2b);
  c3_mfma <<<dim3(1280), dim3(256), 0, stream>>>(o2b, w3, g3, b3, m3, v3, filled, chw, ewb, out);
}

// Round 3
// 514.584 us; speedup vs baseline: 2.4120x; 1.2698x over previous
//
#include <hip/hip_runtime.h>
#include <math.h>

#define BB 8
#define CC 128
#define CH 64
#define HH 160
#define WW 160
#define HW (HH*WW)
#define PP 162            // padded width/height for conv2 input
#define INF __builtin_inff()

typedef __bf16 bfv8 __attribute__((ext_vector_type(8)));
typedef __bf16 bfv4 __attribute__((ext_vector_type(4)));
typedef float  f4   __attribute__((ext_vector_type(4)));

__device__ __forceinline__ float sgm(float z){ return 1.0f/(1.0f + __expf(-z)); }
__device__ __forceinline__ float silu_(float z){ return z/(1.0f + __expf(-z)); }
__device__ __forceinline__ f4 MFMA(bfv8 a, bfv8 b, f4 c){
  return __builtin_amdgcn_mfma_f32_16x16x32_bf16(a, b, c, 0, 0, 0);
}

// clipped 3-point horizontal max/min at column w of row r; returns center
__device__ __forceinline__ float hrow3L(const float* __restrict__ r, int w,
                                        float& hM, float& hm){
  float cv = r[w];
  float M = cv, m = cv;
  if(w > 0){ float l = r[w-1]; M = fmaxf(M,l); m = fminf(m,l); }
  if(w < WW-1){ float rr = r[w+1]; M = fmaxf(M,rr); m = fminf(m,rr); }
  hM = M; hm = m; return cv;
}

// K12: fused stats + fill. One block per (b,c) plane, whole plane staged in LDS.
__global__ __launch_bounds__(256) void k12(const float* __restrict__ x,
                                           const float* __restrict__ fsr,
                                           float* __restrict__ filled,
                                           float* __restrict__ chw){
  extern __shared__ __align__(16) float pl[];   // [160*160] fp32, linear
  __shared__ float ra[256], rb[256];
  __shared__ float sb[2];
  int bc = blockIdx.x;
  int c  = bc & (CC-1);
  int t  = threadIdx.x;
  const float* xp = x + (size_t)bc*HW;
  {
    int wvb = t & ~63;   // wave-uniform LDS base; lane scatter is HW (+lane*16)
    #pragma unroll
    for(int e=0; e<25; ++e){
      const char* g = (const char*)xp + (size_t)(e*256 + t)*16;
      char* l = (char*)pl + (size_t)(e*256 + wvb)*16;
      __builtin_amdgcn_global_load_lds((const __attribute__((address_space(1))) void*)g,
                                       (__attribute__((address_space(3))) void*)l,
                                       16, 0, 0);
    }
  }
  asm volatile("s_waitcnt vmcnt(0)" ::: "memory");
  __syncthreads();

  // pass 1: per-plane min(x) and sum of 3x3 clipped-window contrast
  float mn = INF, sum = 0.f;
  if(t < WW){
    float hMp=-INF, hmp=INF, hMc, hmc, hMn, hmn;
    mn = hrow3L(pl, t, hMc, hmc);
    #pragma unroll 4
    for(int h=0; h<HH; ++h){
      if(h < HH-1){ float cv = hrow3L(pl + (h+1)*WW, t, hMn, hmn); mn = fminf(mn, cv); }
      else { hMn=-INF; hmn=INF; }
      sum += fmaxf(fmaxf(hMp,hMc),hMn) - fminf(fminf(hmp,hmc),hmn);
      hMp=hMc; hmp=hmc; hMc=hMn; hmc=hmn;
    }
  }
  ra[t]=mn; rb[t]=sum; __syncthreads();
  for(int s=128; s>0; s>>=1){
    if(t < s){ ra[t]=fminf(ra[t],ra[t+s]); rb[t]+=rb[t+s]; }
    __syncthreads();
  }
  if(t==0){ sb[0]=ra[0]; sb[1]=0.3f*(rb[0]/(float)HW + 1e-6f); }
  __syncthreads();
  float base = sb[0], th = sb[1];
  float s = sgm(fsr[c]);

  // pass 2: filled + |filled| max/mean -> chw
  float* fp = filled + (size_t)bc*HW;
  float amax=0.f, asum=0.f;
  if(t < WW){
    float hMp=-INF, hmp=INF, hMc, hmc, hMn, hmn;
    float cc = hrow3L(pl, t, hMc, hmc);
    #pragma unroll 4
    for(int h=0; h<HH; ++h){
      float cn = 0.f;
      if(h < HH-1) cn = hrow3L(pl + (h+1)*WW, t, hMn, hmn);
      else { hMn=-INF; hmn=INF; }
      float contrast = fmaxf(fmaxf(hMp,hMc),hMn) - fminf(fminf(hmp,hmc),hmn);
      float f = (contrast < th) ? cc*(1.f-s) + base*s : cc;
      fp[h*WW + t] = f;
      float a = fabsf(f);
      amax = fmaxf(amax, a); asum += a;
      hMp=hMc; hmp=hmc; hMc=hMn; hmc=hmn; cc = cn;
    }
  }
  ra[t]=amax; rb[t]=asum; __syncthreads();
  for(int st=128; st>0; st>>=1){
    if(t < st){ ra[t]=fmaxf(ra[t],ra[t+st]); rb[t]+=rb[t+st]; }
    __syncthreads();
  }
  if(t==0) chw[bc] = sgm(3.0f*(ra[0] - rb[0]/(float)HW - 0.3f));
}

// K3: xs[b,p] = mean_c |filled|, vectorized f4
__global__ __launch_bounds__(256) void k3_xs(const float* __restrict__ filled,
                                             float* __restrict__ xs){
  int i = blockIdx.x*256 + threadIdx.x;       // BB*HW/4 units
  int b = i / (HW/4); int p4 = (i - b*(HW/4))*4;
  const float* fp = filled + (size_t)b*CC*HW + p4;
  f4 s = {0.f,0.f,0.f,0.f};
  #pragma unroll 4
  for(int c=0; c<CC; ++c){
    f4 v = *(const f4*)(fp + (size_t)c*HW);
    s.x += fabsf(v.x); s.y += fabsf(v.y); s.z += fabsf(v.z); s.w += fabsf(v.w);
  }
  f4 r = {s.x*(1.f/CC), s.y*(1.f/CC), s.z*(1.f/CC), s.w*(1.f/CC)};
  *(f4*)(xs + (size_t)b*HW + p4) = r;
}

// K4: edge weight via rolling 3x3 contrast on xs; strips of 32 rows
__global__ __launch_bounds__(256) void k4_ew(const float* __restrict__ xs,
                                             float* __restrict__ ew){
  int b  = blockIdx.x / 5;
  int r0 = (blockIdx.x % 5) * 32;
  int w  = threadIdx.x;
  if(w >= WW) return;
  const float* xp = xs + (size_t)b*HW;
  float* ep = ew + (size_t)b*HW;
  float hMp, hmp, hMc, hmc, hMn, hmn;
  if(r0 > 0) hrow3L(xp + (r0-1)*WW, w, hMp, hmp); else { hMp=-INF; hmp=INF; }
  hrow3L(xp + r0*WW, w, hMc, hmc);
  #pragma unroll 4
  for(int h=r0; h<r0+32; ++h){
    if(h < HH-1) hrow3L(xp + (h+1)*WW, w, hMn, hmn); else { hMn=-INF; hmn=INF; }
    float contrast = fmaxf(fmaxf(hMp,hMc),hMn) - fminf(fminf(hmp,hmc),hmn);
    ep[h*WW + w] = sgm(5.0f*(contrast - 0.5f));
    hMp=hMc; hmp=hmc; hMc=hMn; hmc=hmn;
  }
}

// K5: enh[b][p][ic] (NHWC bf16) = filled * chw * (1+ew), via LDS transpose
__global__ __launch_bounds__(256) void k_enh(const float* __restrict__ filled,
                                             const float* __restrict__ chw,
                                             const float* __restrict__ ew,
                                             __bf16* __restrict__ enh){
  __shared__ __bf16 tile[64][132];
  int b  = blockIdx.x / 400;
  int p0 = (blockIdx.x % 400) * 64;
  int t  = threadIdx.x;
  #pragma unroll 4
  for(int e=0; e<32; ++e){
    int idx = e*256 + t; int ic = idx >> 6; int p = idx & 63;
    float v = filled[((size_t)(b*CC + ic))*HW + p0 + p];
    float g = chw[b*CC + ic] * (1.f + ew[(size_t)b*HW + p0 + p]);
    tile[p][ic] = (__bf16)(v * g);
  }
  __syncthreads();
  #pragma unroll
  for(int e=0; e<8; ++e){
    int idx = e*256 + t; int p = idx >> 5; int icg = idx & 31;
    bfv4 v = *(const bfv4*)&tile[p][icg*4];
    *(bfv4*)&enh[((size_t)(b*HW + p0 + p))*CC + icg*4] = v;
  }
}

// C1: o1p(padded NHWC bf16) = silu(bn1(w1 @ enh));  M=64, K=128, N=pixels
__global__ __launch_bounds__(256) void c1_mfma(const __bf16* __restrict__ enh,
                                               const float* __restrict__ w1,
                                               const float* __restrict__ g1,
                                               const float* __restrict__ b1,
                                               const float* __restrict__ m1,
                                               const float* __restrict__ v1,
                                               __bf16* __restrict__ o1p){
  int lane = threadIdx.x & 63, wv = threadIdx.x >> 6;
  int u = blockIdx.x*4 + wv;            // 2560 units: b(8) x h(160) x half(2)
  int b = u / 320; int r = u % 320; int h = r >> 1; int w0base = (r & 1)*80;
  int q = lane >> 4, j = lane & 15;
  bfv8 afr[4][4];
  #pragma unroll
  for(int mt=0; mt<4; ++mt){
    int oc = mt*16 + j;
    #pragma unroll
    for(int kk=0; kk<4; ++kk){
      const float* wp = w1 + oc*CC + kk*32 + q*8;
      bfv8 a;
      #pragma unroll
      for(int e=0; e<8; ++e) a[e] = (__bf16)wp[e];
      afr[mt][kk] = a;
    }
  }
  float sc[4][4], sh[4][4];
  #pragma unroll
  for(int mt=0; mt<4; ++mt)
    #pragma unroll
    for(int rr=0; rr<4; ++rr){
      int oc = mt*16 + q*4 + rr;
      float s = g1[oc]*rsqrtf(v1[oc] + 1e-5f);
      sc[mt][rr] = s; sh[mt][rr] = b1[oc] - m1[oc]*s;
    }
  const __bf16* ebase = enh + (size_t)b*HW*CC;
  __bf16* obase = o1p + (size_t)b*PP*PP*CH;
  for(int s5=0; s5<5; ++s5){
    int w0 = w0base + s5*16;
    int p0 = h*WW + w0;
    const __bf16* bp = ebase + (size_t)(p0 + j)*CC + q*8;
    bfv8 bf[4];
    #pragma unroll
    for(int kk=0; kk<4; ++kk) bf[kk] = *(const bfv8*)(bp + kk*32);
    f4 acc[4] = {{0,0,0,0},{0,0,0,0},{0,0,0,0},{0,0,0,0}};
    #pragma unroll
    for(int kk=0; kk<4; ++kk)
      #pragma unroll
      for(int mt=0; mt<4; ++mt)
        acc[mt] = MFMA(afr[mt][kk], bf[kk], acc[mt]);
    int w = w0 + j;
    __bf16* op = obase + ((size_t)(h+1)*PP + (w+1))*CH + q*4;
    #pragma unroll
    for(int mt=0; mt<4; ++mt){
      bfv4 ov;
      #pragma unroll
      for(int rr=0; rr<4; ++rr){
        float z = acc[mt][rr]*sc[mt][rr] + sh[mt][rr];
        ov[rr] = (__bf16)silu_(z);
      }
      *(bfv4*)(op + mt*16) = ov;
    }
  }
}

// C2: o2(NHWC bf16) = silu(bn2(conv3x3(o1p, w2))); 9 taps from padded buffer
__global__ __launch_bounds__(256) void c2_mfma(const __bf16* __restrict__ o1p,
                                               const float* __restrict__ w2,
                                               const float* __restrict__ g2,
                                               const float* __restrict__ b2,
                                               const float* __restrict__ m2,
                                               const float* __restrict__ v2,
                                               __bf16* __restrict__ o2){
  int lane = threadIdx.x & 63, mt = threadIdx.x >> 6;
  int b = blockIdx.x / HH, h = blockIdx.x % HH;
  int q = lane >> 4, j = lane & 15;
  int oc = mt*16 + j;
  bfv8 afr[9][2];
  #pragma unroll
  for(int t=0; t<9; ++t)
    #pragma unroll
    for(int icb=0; icb<2; ++icb){
      const float* wp = w2 + ((size_t)oc*CH + icb*32 + q*8)*9 + t;
      bfv8 a;
      #pragma unroll
      for(int e=0; e<8; ++e) a[e] = (__bf16)wp[e*9];
      afr[t][icb] = a;
    }
  float sc[4], sh[4];
  #pragma unroll
  for(int rr=0; rr<4; ++rr){
    int o = mt*16 + q*4 + rr;
    float s = g2[o]*rsqrtf(v2[o] + 1e-5f);
    sc[rr] = s; sh[rr] = b2[o] - m2[o]*s;
  }
  const __bf16* ibase = o1p + (size_t)b*PP*PP*CH;
  __bf16* obase = o2 + (size_t)b*HW*CH;
  for(int w0=0; w0<WW; w0+=16){
    f4 acc = {0.f,0.f,0.f,0.f};
    #pragma unroll
    for(int dh=0; dh<3; ++dh){
      const __bf16* rp = ibase + ((size_t)(h+dh)*PP + w0 + j)*CH + q*8;
      #pragma unroll
      for(int dw=0; dw<3; ++dw)
        #pragma unroll
        for(int icb=0; icb<2; ++icb){
          bfv8 bf = *(const bfv8*)(rp + dw*CH + icb*32);
          acc = MFMA(afr[dh*3+dw][icb], bf, acc);
        }
    }
    __bf16* op = obase + ((size_t)(h*WW + w0 + j))*CH + mt*16 + q*4;
    bfv4 ov;
    #pragma unroll
    for(int rr=0; rr<4; ++rr){
      float z = acc[rr]*sc[rr] + sh[rr];
      ov[rr] = (__bf16)silu_(z);
    }
    *(bfv4*)op = ov;
  }
}

// C3: out(NCHW f32) = silu(bn3(w3 @ o2) + filled*chw*(1+ew)); M=128, K=64
__global__ __launch_bounds__(256) void c3_mfma(const __bf16* __restrict__ o2,
                                               const float* __restrict__ w3,
                                               const float* __restrict__ g3,
                                               const float* __restrict__ b3,
                                               const float* __restrict__ m3,
                                               const float* __restrict__ v3,
                                               const float* __restrict__ filled,
                                               const float* __restrict__ chw,
                                               const float* __restrict__ ew,
                                               float* __restrict__ out){
  int lane = threadIdx.x & 63, wv = threadIdx.x >> 6;
  int u = blockIdx.x*4 + wv;            // 5120 units: b x h x seg(2) x ochalf(2)
  int b = u / 640; int r = u % 640; int h = r >> 2; int t = r & 3;
  int oh = t & 1; int w0base = (t >> 1)*80;
  int q = lane >> 4, j = lane & 15;
  bfv8 afr[4][2];
  #pragma unroll
  for(int mt=0; mt<4; ++mt){
    int oc = oh*64 + mt*16 + j;
    #pragma unroll
    for(int kk=0; kk<2; ++kk){
      const float* wp = w3 + oc*CH + kk*32 + q*8;
      bfv8 a;
      #pragma unroll
      for(int e=0; e<8; ++e) a[e] = (__bf16)wp[e];
      afr[mt][kk] = a;
    }
  }
  float sc[4][4], sh[4][4], cw[4][4];
  #pragma unroll
  for(int mt=0; mt<4; ++mt)
    #pragma unroll
    for(int rr=0; rr<4; ++rr){
      int oc = oh*64 + mt*16 + q*4 + rr;
      float s = g3[oc]*rsqrtf(v3[oc] + 1e-5f);
      sc[mt][rr] = s; sh[mt][rr] = b3[oc] - m3[oc]*s;
      cw[mt][rr] = chw[b*CC + oc];
    }
  const __bf16* ibase = o2 + (size_t)b*HW*CH;
  for(int s5=0; s5<5; ++s5){
    int w0 = w0base + s5*16;
    int p0 = h*WW + w0;
    int pix = p0 + j;
    const __bf16* bp = ibase + (size_t)pix*CH + q*8;
    bfv8 bf0 = *(const bfv8*)bp;
    bfv8 bf1 = *(const bfv8*)(bp + 32);
    f4 acc[4] = {{0,0,0,0},{0,0,0,0},{0,0,0,0},{0,0,0,0}};
    #pragma unroll
    for(int mt=0; mt<4; ++mt){
      acc[mt] = MFMA(afr[mt][0], bf0, acc[mt]);
      acc[mt] = MFMA(afr[mt][1], bf1, acc[mt]);
    }
    float ewv = 1.f + ew[(size_t)b*HW + pix];
    #pragma unroll
    for(int mt=0; mt<4; ++mt)
      #pragma unroll
      for(int rr=0; rr<4; ++rr){
        int oc = oh*64 + mt*16 + q*4 + rr;
        size_t gix = ((size_t)(b*CC + oc))*HW + pix;
        float res = filled[gix] * cw[mt][rr] * ewv;
        float z = acc[mt][rr]*sc[mt][rr] + sh[mt][rr] + res;
        out[gix] = silu_(z);
      }
  }
}

extern "C" void kernel_launch(void* const* d_in, const int* in_sizes, int n_in,
                              void* d_out, int out_size, void* d_ws, size_t ws_size,
                              hipStream_t stream) {
  const float* x   = (const float*)d_in[0];
  const float* fsr = (const float*)d_in[1];
  const float* w1  = (const float*)d_in[2];
  const float* g1  = (const float*)d_in[3];
  const float* b1  = (const float*)d_in[4];
  const float* m1  = (const float*)d_in[5];
  const float* v1  = (const float*)d_in[6];
  const float* w2  = (const float*)d_in[7];
  const float* g2  = (const float*)d_in[8];
  const float* b2  = (const float*)d_in[9];
  const float* m2  = (const float*)d_in[10];
  const float* v2  = (const float*)d_in[11];
  const float* w3  = (const float*)d_in[12];
  const float* g3  = (const float*)d_in[13];
  const float* b3  = (const float*)d_in[14];
  const float* m3  = (const float*)d_in[15];
  const float* v3  = (const float*)d_in[16];
  float* out = (float*)d_out;

  char* wp = (char*)d_ws;
  float*  filled = (float*)wp;   wp += (size_t)BB*CC*HW*4;       // 104.9 MB
  __bf16* enh    = (__bf16*)wp;  wp += (size_t)BB*HW*CC*2;       // 52.4 MB
  __bf16* o1p    = (__bf16*)wp;  wp += (size_t)BB*PP*PP*CH*2;    // 26.9 MB
  __bf16* o2b    = (__bf16*)wp;  wp += (size_t)BB*HW*CH*2;       // 26.2 MB
  float*  xs     = (float*)wp;   wp += (size_t)BB*HW*4;
  float*  ewb    = (float*)wp;   wp += (size_t)BB*HW*4;
  float*  chw    = (float*)wp;   wp += 1024*4;

  // allow >64KB dynamic LDS for k12 (102.4 KB plane)
  hipFuncSetAttribute((const void*)k12, hipFuncAttributeMaxDynamicSharedMemorySize, 102400);

  // zero padded conv2 input (borders must be 0 every launch)
  hipMemsetAsync(o1p, 0, (size_t)BB*PP*PP*CH*2, stream);

  k12     <<<dim3(BB*CC), dim3(256), 102400, stream>>>(x, fsr, filled, chw);
  k3_xs   <<<dim3(BB*HW/4/256), dim3(256), 0, stream>>>(filled, xs);
  k4_ew   <<<dim3(BB*5), dim3(256), 0, stream>>>(xs, ewb);
  k_enh   <<<dim3(BB*400), dim3(256), 0, stream>>>(filled, chw, ewb, enh);
  c1_mfma <<<dim3(640), dim3(256), 0, stream>>>(enh, w1, g1, b1, m1, v1, o1p);
  c2_mfma <<<dim3(BB*HH), dim3(256), 0, stream>>>(o1p, w2, g2, b2, m2, v2, o2b);
  c3_mfma <<<dim3(1280), dim3(256), 0, stream>>>(o2b, w3, g3, b3, m3, v3, filled, chw, ewb, out);
}

// Round 4
// 432.418 us; speedup vs baseline: 2.8703x; 1.1900x over previous
//
#include <hip/hip_runtime.h>
#include <math.h>

#define BB 8
#define CC 128
#define CH 64
#define HH 160
#define WW 160
#define HW (HH*WW)
#define PP 162            // padded width/height for conv2 input
#define INF __builtin_inff()

typedef __bf16 bfv8 __attribute__((ext_vector_type(8)));
typedef __bf16 bfv4 __attribute__((ext_vector_type(4)));
typedef float  f4   __attribute__((ext_vector_type(4)));

__device__ __forceinline__ float sgm(float z){ return 1.0f/(1.0f + __expf(-z)); }
__device__ __forceinline__ float silu_(float z){ return z/(1.0f + __expf(-z)); }
__device__ __forceinline__ f4 MFMA(bfv8 a, bfv8 b, f4 c){
  return __builtin_amdgcn_mfma_f32_16x16x32_bf16(a, b, c, 0, 0, 0);
}

// clipped 3-point horizontal max/min at column w of row r; returns center
__device__ __forceinline__ float hrow3L(const float* __restrict__ r, int w,
                                        float& hM, float& hm){
  float cv = r[w];
  float M = cv, m = cv;
  if(w > 0){ float l = r[w-1]; M = fmaxf(M,l); m = fminf(m,l); }
  if(w < WW-1){ float rr = r[w+1]; M = fmaxf(M,rr); m = fminf(m,rr); }
  hM = M; hm = m; return cv;
}

// K12: fused stats + fill. One block per (b,c) plane; batched global loads
// (4 rows of L/C/R triples issued before any combine) to hide L2/L3 latency.
// Reduction trees and per-column serial h-order kept IDENTICAL to the
// previous passing version (thr is reassociation-sensitive).
__global__ __launch_bounds__(256) void k12(const float* __restrict__ x,
                                           const float* __restrict__ fsr,
                                           float* __restrict__ filled,
                                           float* __restrict__ chw){
  __shared__ float ra[256], rb[256];
  __shared__ float sb[2];
  int bc = blockIdx.x;
  int c  = bc & (CC-1);
  int t  = threadIdx.x;
  const float* xp = x + (size_t)bc*HW;
  bool act  = t < WW;
  bool hasL = t > 0, hasR = t < WW-1;

  // ---- pass 1: per-plane min(x) and sum of 3x3 clipped-window contrast ----
  float mn = INF, sum = 0.f;
  float Mp = -INF, mp = INF, Mc = -INF, mc = INF;
  if(act){
    float cv = xp[t];
    float l  = hasL ? xp[t-1] : 0.f;
    float r  = hasR ? xp[t+1] : 0.f;
    float ML = hasL ? l : -INF, MR = hasR ? r : -INF;
    float mL = hasL ? l :  INF, mR = hasR ? r :  INF;
    Mc = fmaxf(cv, fmaxf(ML, MR)); mc = fminf(cv, fminf(mL, mR));
    mn = cv;
  }
  for(int h0=0; h0<HH; h0+=4){
    float L[4], C[4], R[4];
    #pragma unroll
    for(int k=0;k<4;++k){
      int hr = h0+1+k;
      if(act && hr < HH){
        const float* rp = xp + hr*WW;
        L[k] = hasL ? rp[t-1] : 0.f; C[k] = rp[t]; R[k] = hasR ? rp[t+1] : 0.f;
      } else { L[k]=0.f; C[k]=0.f; R[k]=0.f; }
    }
    if(act){
      #pragma unroll
      for(int k=0;k<4;++k){
        int hr = h0+1+k;
        float Mn, mr;
        if(hr < HH){
          float ML = hasL ? L[k] : -INF, MR = hasR ? R[k] : -INF;
          float mL = hasL ? L[k] :  INF, mRr = hasR ? R[k] :  INF;
          Mn = fmaxf(C[k], fmaxf(ML,MR)); mr = fminf(C[k], fminf(mL,mRr));
          mn = fminf(mn, C[k]);
        } else { Mn = -INF; mr = INF; }
        sum += fmaxf(fmaxf(Mp,Mc),Mn) - fminf(fminf(mp,mc),mr);
        Mp=Mc; mp=mc; Mc=Mn; mc=mr;
      }
    }
  }
  ra[t]=mn; rb[t]=sum; __syncthreads();
  for(int s=128; s>0; s>>=1){
    if(t < s){ ra[t]=fminf(ra[t],ra[t+s]); rb[t]+=rb[t+s]; }
    __syncthreads();
  }
  if(t==0){ sb[0]=ra[0]; sb[1]=0.3f*(rb[0]/(float)HW + 1e-6f); }
  __syncthreads();
  float base = sb[0], th = sb[1];
  float s = sgm(fsr[c]);

  // ---- pass 2: filled + |filled| max/mean -> chw ----
  float* fp = filled + (size_t)bc*HW;
  float amax=0.f, asum=0.f;
  Mp=-INF; mp=INF; Mc=-INF; mc=INF;
  float cen = 0.f;
  if(act){
    float cv = xp[t];
    float l  = hasL ? xp[t-1] : 0.f;
    float r  = hasR ? xp[t+1] : 0.f;
    float ML = hasL ? l : -INF, MR = hasR ? r : -INF;
    float mL = hasL ? l :  INF, mR = hasR ? r :  INF;
    Mc = fmaxf(cv, fmaxf(ML, MR)); mc = fminf(cv, fminf(mL, mR));
    cen = cv;
  }
  for(int h0=0; h0<HH; h0+=4){
    float L[4], C[4], R[4];
    #pragma unroll
    for(int k=0;k<4;++k){
      int hr = h0+1+k;
      if(act && hr < HH){
        const float* rp = xp + hr*WW;
        L[k] = hasL ? rp[t-1] : 0.f; C[k] = rp[t]; R[k] = hasR ? rp[t+1] : 0.f;
      } else { L[k]=0.f; C[k]=0.f; R[k]=0.f; }
    }
    if(act){
      #pragma unroll
      for(int k=0;k<4;++k){
        int hr = h0+1+k;
        int h  = h0+k;
        float Mn, mr;
        if(hr < HH){
          float ML = hasL ? L[k] : -INF, MR = hasR ? R[k] : -INF;
          float mL = hasL ? L[k] :  INF, mRr = hasR ? R[k] :  INF;
          Mn = fmaxf(C[k], fmaxf(ML,MR)); mr = fminf(C[k], fminf(mL,mRr));
        } else { Mn = -INF; mr = INF; }
        float contrast = fmaxf(fmaxf(Mp,Mc),Mn) - fminf(fminf(mp,mc),mr);
        float f = (contrast < th) ? cen*(1.f-s) + base*s : cen;
        fp[h*WW + t] = f;
        float a = fabsf(f);
        amax = fmaxf(amax, a); asum += a;
        Mp=Mc; mp=mc; Mc=Mn; mc=mr; cen = C[k];
      }
    }
  }
  ra[t]=amax; rb[t]=asum; __syncthreads();
  for(int st=128; st>0; st>>=1){
    if(t < st){ ra[t]=fmaxf(ra[t],ra[t+st]); rb[t]+=rb[t+st]; }
    __syncthreads();
  }
  if(t==0) chw[bc] = sgm(3.0f*(ra[0] - rb[0]/(float)HW - 0.3f));
}

// K3: xs[b,p] = mean_c |filled|, vectorized f4
__global__ __launch_bounds__(256) void k3_xs(const float* __restrict__ filled,
                                             float* __restrict__ xs){
  int i = blockIdx.x*256 + threadIdx.x;       // BB*HW/4 units
  int b = i / (HW/4); int p4 = (i - b*(HW/4))*4;
  const float* fp = filled + (size_t)b*CC*HW + p4;
  f4 s = {0.f,0.f,0.f,0.f};
  #pragma unroll 4
  for(int c=0; c<CC; ++c){
    f4 v = *(const f4*)(fp + (size_t)c*HW);
    s.x += fabsf(v.x); s.y += fabsf(v.y); s.z += fabsf(v.z); s.w += fabsf(v.w);
  }
  f4 r = {s.x*(1.f/CC), s.y*(1.f/CC), s.z*(1.f/CC), s.w*(1.f/CC)};
  *(f4*)(xs + (size_t)b*HW + p4) = r;
}

// K4: edge weight via rolling 3x3 contrast on xs; strips of 32 rows
__global__ __launch_bounds__(256) void k4_ew(const float* __restrict__ xs,
                                             float* __restrict__ ew){
  int b  = blockIdx.x / 5;
  int r0 = (blockIdx.x % 5) * 32;
  int w  = threadIdx.x;
  if(w >= WW) return;
  const float* xp = xs + (size_t)b*HW;
  float* ep = ew + (size_t)b*HW;
  float hMp, hmp, hMc, hmc, hMn, hmn;
  if(r0 > 0) hrow3L(xp + (r0-1)*WW, w, hMp, hmp); else { hMp=-INF; hmp=INF; }
  hrow3L(xp + r0*WW, w, hMc, hmc);
  #pragma unroll 4
  for(int h=r0; h<r0+32; ++h){
    if(h < HH-1) hrow3L(xp + (h+1)*WW, w, hMn, hmn); else { hMn=-INF; hmn=INF; }
    float contrast = fmaxf(fmaxf(hMp,hMc),hMn) - fminf(fminf(hmp,hmc),hmn);
    ep[h*WW + w] = sgm(5.0f*(contrast - 0.5f));
    hMp=hMc; hmp=hmc; hMc=hMn; hmc=hmn;
  }
}

// K5: enh[b][p][ic] (NHWC bf16) = filled * chw * (1+ew), via LDS transpose
__global__ __launch_bounds__(256) void k_enh(const float* __restrict__ filled,
                                             const float* __restrict__ chw,
                                             const float* __restrict__ ew,
                                             __bf16* __restrict__ enh){
  __shared__ __bf16 tile[64][132];
  int b  = blockIdx.x / 400;
  int p0 = (blockIdx.x % 400) * 64;
  int t  = threadIdx.x;
  #pragma unroll 4
  for(int e=0; e<32; ++e){
    int idx = e*256 + t; int ic = idx >> 6; int p = idx & 63;
    float v = filled[((size_t)(b*CC + ic))*HW + p0 + p];
    float g = chw[b*CC + ic] * (1.f + ew[(size_t)b*HW + p0 + p]);
    tile[p][ic] = (__bf16)(v * g);
  }
  __syncthreads();
  #pragma unroll
  for(int e=0; e<8; ++e){
    int idx = e*256 + t; int p = idx >> 5; int icg = idx & 31;
    bfv4 v = *(const bfv4*)&tile[p][icg*4];
    *(bfv4*)&enh[((size_t)(b*HW + p0 + p))*CC + icg*4] = v;
  }
}

// C1: o1p(padded NHWC bf16) = silu(bn1(w1 @ enh));  M=64, K=128, N=pixels
__global__ __launch_bounds__(256) void c1_mfma(const __bf16* __restrict__ enh,
                                               const float* __restrict__ w1,
                                               const float* __restrict__ g1,
                                               const float* __restrict__ b1,
                                               const float* __restrict__ m1,
                                               const float* __restrict__ v1,
                                               __bf16* __restrict__ o1p){
  int lane = threadIdx.x & 63, wv = threadIdx.x >> 6;
  int u = blockIdx.x*4 + wv;            // 2560 units: b(8) x h(160) x half(2)
  int b = u / 320; int r = u % 320; int h = r >> 1; int w0base = (r & 1)*80;
  int q = lane >> 4, j = lane & 15;
  bfv8 afr[4][4];
  #pragma unroll
  for(int mt=0; mt<4; ++mt){
    int oc = mt*16 + j;
    #pragma unroll
    for(int kk=0; kk<4; ++kk){
      const float* wp = w1 + oc*CC + kk*32 + q*8;
      bfv8 a;
      #pragma unroll
      for(int e=0; e<8; ++e) a[e] = (__bf16)wp[e];
      afr[mt][kk] = a;
    }
  }
  float sc[4][4], sh[4][4];
  #pragma unroll
  for(int mt=0; mt<4; ++mt)
    #pragma unroll
    for(int rr=0; rr<4; ++rr){
      int oc = mt*16 + q*4 + rr;
      float s = g1[oc]*rsqrtf(v1[oc] + 1e-5f);
      sc[mt][rr] = s; sh[mt][rr] = b1[oc] - m1[oc]*s;
    }
  const __bf16* ebase = enh + (size_t)b*HW*CC;
  __bf16* obase = o1p + (size_t)b*PP*PP*CH;
  for(int s5=0; s5<5; ++s5){
    int w0 = w0base + s5*16;
    int p0 = h*WW + w0;
    const __bf16* bp = ebase + (size_t)(p0 + j)*CC + q*8;
    bfv8 bf[4];
    #pragma unroll
    for(int kk=0; kk<4; ++kk) bf[kk] = *(const bfv8*)(bp + kk*32);
    f4 acc[4] = {{0,0,0,0},{0,0,0,0},{0,0,0,0},{0,0,0,0}};
    #pragma unroll
    for(int kk=0; kk<4; ++kk)
      #pragma unroll
      for(int mt=0; mt<4; ++mt)
        acc[mt] = MFMA(afr[mt][kk], bf[kk], acc[mt]);
    int w = w0 + j;
    __bf16* op = obase + ((size_t)(h+1)*PP + (w+1))*CH + q*4;
    #pragma unroll
    for(int mt=0; mt<4; ++mt){
      bfv4 ov;
      #pragma unroll
      for(int rr=0; rr<4; ++rr){
        float z = acc[mt][rr]*sc[mt][rr] + sh[mt][rr];
        ov[rr] = (__bf16)silu_(z);
      }
      *(bfv4*)(op + mt*16) = ov;
    }
  }
}

// C2: o2(NHWC bf16) = silu(bn2(conv3x3(o1p, w2))); 9 taps from padded buffer
__global__ __launch_bounds__(256) void c2_mfma(const __bf16* __restrict__ o1p,
                                               const float* __restrict__ w2,
                                               const float* __restrict__ g2,
                                               const float* __restrict__ b2,
                                               const float* __restrict__ m2,
                                               const float* __restrict__ v2,
                                               __bf16* __restrict__ o2){
  int lane = threadIdx.x & 63, mt = threadIdx.x >> 6;
  int b = blockIdx.x / HH, h = blockIdx.x % HH;
  int q = lane >> 4, j = lane & 15;
  int oc = mt*16 + j;
  bfv8 afr[9][2];
  #pragma unroll
  for(int t=0; t<9; ++t)
    #pragma unroll
    for(int icb=0; icb<2; ++icb){
      const float* wp = w2 + ((size_t)oc*CH + icb*32 + q*8)*9 + t;
      bfv8 a;
      #pragma unroll
      for(int e=0; e<8; ++e) a[e] = (__bf16)wp[e*9];
      afr[t][icb] = a;
    }
  float sc[4], sh[4];
  #pragma unroll
  for(int rr=0; rr<4; ++rr){
    int o = mt*16 + q*4 + rr;
    float s = g2[o]*rsqrtf(v2[o] + 1e-5f);
    sc[rr] = s; sh[rr] = b2[o] - m2[o]*s;
  }
  const __bf16* ibase = o1p + (size_t)b*PP*PP*CH;
  __bf16* obase = o2 + (size_t)b*HW*CH;
  for(int w0=0; w0<WW; w0+=16){
    f4 acc = {0.f,0.f,0.f,0.f};
    #pragma unroll
    for(int dh=0; dh<3; ++dh){
      const __bf16* rp = ibase + ((size_t)(h+dh)*PP + w0 + j)*CH + q*8;
      #pragma unroll
      for(int dw=0; dw<3; ++dw)
        #pragma unroll
        for(int icb=0; icb<2; ++icb){
          bfv8 bf = *(const bfv8*)(rp + dw*CH + icb*32);
          acc = MFMA(afr[dh*3+dw][icb], bf, acc);
        }
    }
    __bf16* op = obase + ((size_t)(h*WW + w0 + j))*CH + mt*16 + q*4;
    bfv4 ov;
    #pragma unroll
    for(int rr=0; rr<4; ++rr){
      float z = acc[rr]*sc[rr] + sh[rr];
      ov[rr] = (__bf16)silu_(z);
    }
    *(bfv4*)op = ov;
  }
}

// C3: out(NCHW f32) = silu(bn3(w3 @ o2) + filled*chw*(1+ew)); M=128, K=64
__global__ __launch_bounds__(256) void c3_mfma(const __bf16* __restrict__ o2,
                                               const float* __restrict__ w3,
                                               const float* __restrict__ g3,
                                               const float* __restrict__ b3,
                                               const float* __restrict__ m3,
                                               const float* __restrict__ v3,
                                               const float* __restrict__ filled,
                                               const float* __restrict__ chw,
                                               const float* __restrict__ ew,
                                               float* __restrict__ out){
  int lane = threadIdx.x & 63, wv = threadIdx.x >> 6;
  int u = blockIdx.x*4 + wv;            // 5120 units: b x h x seg(2) x ochalf(2)
  int b = u / 640; int r = u % 640; int h = r >> 2; int t = r & 3;
  int oh = t & 1; int w0base = (t >> 1)*80;
  int q = lane >> 4, j = lane & 15;
  bfv8 afr[4][2];
  #pragma unroll
  for(int mt=0; mt<4; ++mt){
    int oc = oh*64 + mt*16 + j;
    #pragma unroll
    for(int kk=0; kk<2; ++kk){
      const float* wp = w3 + oc*CH + kk*32 + q*8;
      bfv8 a;
      #pragma unroll
      for(int e=0; e<8; ++e) a[e] = (__bf16)wp[e];
      afr[mt][kk] = a;
    }
  }
  float sc[4][4], sh[4][4], cw[4][4];
  #pragma unroll
  for(int mt=0; mt<4; ++mt)
    #pragma unroll
    for(int rr=0; rr<4; ++rr){
      int oc = oh*64 + mt*16 + q*4 + rr;
      float s = g3[oc]*rsqrtf(v3[oc] + 1e-5f);
      sc[mt][rr] = s; sh[mt][rr] = b3[oc] - m3[oc]*s;
      cw[mt][rr] = chw[b*CC + oc];
    }
  const __bf16* ibase = o2 + (size_t)b*HW*CH;
  for(int s5=0; s5<5; ++s5){
    int w0 = w0base + s5*16;
    int p0 = h*WW + w0;
    int pix = p0 + j;
    const __bf16* bp = ibase + (size_t)pix*CH + q*8;
    bfv8 bf0 = *(const bfv8*)bp;
    bfv8 bf1 = *(const bfv8*)(bp + 32);
    f4 acc[4] = {{0,0,0,0},{0,0,0,0},{0,0,0,0},{0,0,0,0}};
    #pragma unroll
    for(int mt=0; mt<4; ++mt){
      acc[mt] = MFMA(afr[mt][0], bf0, acc[mt]);
      acc[mt] = MFMA(afr[mt][1], bf1, acc[mt]);
    }
    float ewv = 1.f + ew[(size_t)b*HW + pix];
    #pragma unroll
    for(int mt=0; mt<4; ++mt)
      #pragma unroll
      for(int rr=0; rr<4; ++rr){
        int oc = oh*64 + mt*16 + q*4 + rr;
        size_t gix = ((size_t)(b*CC + oc))*HW + pix;
        float res = filled[gix] * cw[mt][rr] * ewv;
        float z = acc[mt][rr]*sc[mt][rr] + sh[mt][rr] + res;
        out[gix] = silu_(z);
      }
  }
}

extern "C" void kernel_launch(void* const* d_in, const int* in_sizes, int n_in,
                              void* d_out, int out_size, void* d_ws, size_t ws_size,
                              hipStream_t stream) {
  const float* x   = (const float*)d_in[0];
  const float* fsr = (const float*)d_in[1];
  const float* w1  = (const float*)d_in[2];
  const float* g1  = (const float*)d_in[3];
  const float* b1  = (const float*)d_in[4];
  const float* m1  = (const float*)d_in[5];
  const float* v1  = (const float*)d_in[6];
  const float* w2  = (const float*)d_in[7];
  const float* g2  = (const float*)d_in[8];
  const float* b2  = (const float*)d_in[9];
  const float* m2  = (const float*)d_in[10];
  const float* v2  = (const float*)d_in[11];
  const float* w3  = (const float*)d_in[12];
  const float* g3  = (const float*)d_in[13];
  const float* b3  = (const float*)d_in[14];
  const float* m3  = (const float*)d_in[15];
  const float* v3  = (const float*)d_in[16];
  float* out = (float*)d_out;

  char* wp = (char*)d_ws;
  float*  filled = (float*)wp;   wp += (size_t)BB*CC*HW*4;       // 104.9 MB
  __bf16* enh    = (__bf16*)wp;  wp += (size_t)BB*HW*CC*2;       // 52.4 MB
  __bf16* o1p    = (__bf16*)wp;  wp += (size_t)BB*PP*PP*CH*2;    // 26.9 MB
  __bf16* o2b    = (__bf16*)wp;  wp += (size_t)BB*HW*CH*2;       // 26.2 MB
  float*  xs     = (float*)wp;   wp += (size_t)BB*HW*4;
  float*  ewb    = (float*)wp;   wp += (size_t)BB*HW*4;
  float*  chw    = (float*)wp;   wp += 1024*4;

  // zero padded conv2 input (borders must be 0 every launch)
  hipMemsetAsync(o1p, 0, (size_t)BB*PP*PP*CH*2, stream);

  k12     <<<dim3(BB*CC), dim3(256), 0, stream>>>(x, fsr, filled, chw);
  k3_xs   <<<dim3(BB*HW/4/256), dim3(256), 0, stream>>>(filled, xs);
  k4_ew   <<<dim3(BB*5), dim3(256), 0, stream>>>(xs, ewb);
  k_enh   <<<dim3(BB*400), dim3(256), 0, stream>>>(filled, chw, ewb, enh);
  c1_mfma <<<dim3(640), dim3(256), 0, stream>>>(enh, w1, g1, b1, m1, v1, o1p);
  c2_mfma <<<dim3(BB*HH), dim3(256), 0, stream>>>(o1p, w2, g2, b2, m2, v2, o2b);
  c3_mfma <<<dim3(1280), dim3(256), 0, stream>>>(o2b, w3, g3, b3, m3, v3, filled, chw, ewb, out);
}

// Round 5
// 328.243 us; speedup vs baseline: 3.7813x; 1.3174x over previous
//
#include <hip/hip_runtime.h>
#include <math.h>

#define BB 8
#define CC 128
#define CH 64
#define HH 160
#define WW 160
#define HW (HH*WW)
#define PP 162            // padded width/height for conv2 input
#define INF __builtin_inff()

typedef __bf16 bfv8 __attribute__((ext_vector_type(8)));
typedef __bf16 bfv4 __attribute__((ext_vector_type(4)));
typedef float  f4   __attribute__((ext_vector_type(4)));

__device__ __forceinline__ float sgm(float z){ return 1.0f/(1.0f + __expf(-z)); }
__device__ __forceinline__ float silu_(float z){ return z/(1.0f + __expf(-z)); }
__device__ __forceinline__ f4 MFMA(bfv8 a, bfv8 b, f4 c){
  return __builtin_amdgcn_mfma_f32_16x16x32_bf16(a, b, c, 0, 0, 0);
}

// clipped 3-point horizontal max/min at column w of row r; returns center
__device__ __forceinline__ float hrow3L(const float* __restrict__ r, int w,
                                        float& hM, float& hm){
  float cv = r[w];
  float M = cv, m = cv;
  if(w > 0){ float l = r[w-1]; M = fmaxf(M,l); m = fminf(m,l); }
  if(w < WW-1){ float rr = r[w+1]; M = fmaxf(M,rr); m = fminf(m,rr); }
  hM = M; hm = m; return cv;
}

// KPREP: bf16 weights (w2 transposed to [tap][oc][ic]) + folded BN scale/shift
__global__ __launch_bounds__(256) void kprep(const float* __restrict__ w1,
                                             const float* __restrict__ g1, const float* __restrict__ b1,
                                             const float* __restrict__ m1, const float* __restrict__ v1,
                                             const float* __restrict__ w2,
                                             const float* __restrict__ g2, const float* __restrict__ b2,
                                             const float* __restrict__ m2, const float* __restrict__ v2,
                                             const float* __restrict__ w3,
                                             const float* __restrict__ g3, const float* __restrict__ b3,
                                             const float* __restrict__ m3, const float* __restrict__ v3,
                                             __bf16* __restrict__ w1b, __bf16* __restrict__ w2b,
                                             __bf16* __restrict__ w3b, float* __restrict__ scsh){
  int t = blockIdx.x*256 + threadIdx.x;
  int stride = gridDim.x*256;
  for(int i=t; i<CH*CC; i+=stride) w1b[i] = (__bf16)w1[i];
  for(int i=t; i<CC*CH; i+=stride) w3b[i] = (__bf16)w3[i];
  for(int i=t; i<9*CH*CH; i+=stride){
    int tap = i >> 12; int rem = i & 4095; int oc = rem >> 6; int ic = rem & 63;
    w2b[i] = (__bf16)w2[(oc*CH + ic)*9 + tap];
  }
  if(t < CH){
    float s = g1[t]*rsqrtf(v1[t] + 1e-5f);
    scsh[t] = s; scsh[64+t] = b1[t] - m1[t]*s;
    float s2 = g2[t]*rsqrtf(v2[t] + 1e-5f);
    scsh[128+t] = s2; scsh[192+t] = b2[t] - m2[t]*s2;
  }
  if(t >= 64 && t < 64+CC){
    int c = t - 64;
    float s3 = g3[c]*rsqrtf(v3[c] + 1e-5f);
    scsh[256+c] = s3; scsh[384+c] = b3[c] - m3[c]*s3;
  }
}

// K12: fused stats + fill. One block per (b,c) plane; batched global loads.
__global__ __launch_bounds__(256) void k12(const float* __restrict__ x,
                                           const float* __restrict__ fsr,
                                           float* __restrict__ filled,
                                           float* __restrict__ chw){
  __shared__ float ra[256], rb[256];
  __shared__ float sb[2];
  int bc = blockIdx.x;
  int c  = bc & (CC-1);
  int t  = threadIdx.x;
  const float* xp = x + (size_t)bc*HW;
  bool act  = t < WW;
  bool hasL = t > 0, hasR = t < WW-1;

  float mn = INF, sum = 0.f;
  float Mp = -INF, mp = INF, Mc = -INF, mc = INF;
  if(act){
    float cv = xp[t];
    float l  = hasL ? xp[t-1] : 0.f;
    float r  = hasR ? xp[t+1] : 0.f;
    float ML = hasL ? l : -INF, MR = hasR ? r : -INF;
    float mL = hasL ? l :  INF, mR = hasR ? r :  INF;
    Mc = fmaxf(cv, fmaxf(ML, MR)); mc = fminf(cv, fminf(mL, mR));
    mn = cv;
  }
  for(int h0=0; h0<HH; h0+=4){
    float L[4], C[4], R[4];
    #pragma unroll
    for(int k=0;k<4;++k){
      int hr = h0+1+k;
      if(act && hr < HH){
        const float* rp = xp + hr*WW;
        L[k] = hasL ? rp[t-1] : 0.f; C[k] = rp[t]; R[k] = hasR ? rp[t+1] : 0.f;
      } else { L[k]=0.f; C[k]=0.f; R[k]=0.f; }
    }
    if(act){
      #pragma unroll
      for(int k=0;k<4;++k){
        int hr = h0+1+k;
        float Mn, mr;
        if(hr < HH){
          float ML = hasL ? L[k] : -INF, MR = hasR ? R[k] : -INF;
          float mL = hasL ? L[k] :  INF, mRr = hasR ? R[k] :  INF;
          Mn = fmaxf(C[k], fmaxf(ML,MR)); mr = fminf(C[k], fminf(mL,mRr));
          mn = fminf(mn, C[k]);
        } else { Mn = -INF; mr = INF; }
        sum += fmaxf(fmaxf(Mp,Mc),Mn) - fminf(fminf(mp,mc),mr);
        Mp=Mc; mp=mc; Mc=Mn; mc=mr;
      }
    }
  }
  ra[t]=mn; rb[t]=sum; __syncthreads();
  for(int s=128; s>0; s>>=1){
    if(t < s){ ra[t]=fminf(ra[t],ra[t+s]); rb[t]+=rb[t+s]; }
    __syncthreads();
  }
  if(t==0){ sb[0]=ra[0]; sb[1]=0.3f*(rb[0]/(float)HW + 1e-6f); }
  __syncthreads();
  float base = sb[0], th = sb[1];
  float s = sgm(fsr[c]);

  float* fp = filled + (size_t)bc*HW;
  float amax=0.f, asum=0.f;
  Mp=-INF; mp=INF; Mc=-INF; mc=INF;
  float cen = 0.f;
  if(act){
    float cv = xp[t];
    float l  = hasL ? xp[t-1] : 0.f;
    float r  = hasR ? xp[t+1] : 0.f;
    float ML = hasL ? l : -INF, MR = hasR ? r : -INF;
    float mL = hasL ? l :  INF, mR = hasR ? r :  INF;
    Mc = fmaxf(cv, fmaxf(ML, MR)); mc = fminf(cv, fminf(mL, mR));
    cen = cv;
  }
  for(int h0=0; h0<HH; h0+=4){
    float L[4], C[4], R[4];
    #pragma unroll
    for(int k=0;k<4;++k){
      int hr = h0+1+k;
      if(act && hr < HH){
        const float* rp = xp + hr*WW;
        L[k] = hasL ? rp[t-1] : 0.f; C[k] = rp[t]; R[k] = hasR ? rp[t+1] : 0.f;
      } else { L[k]=0.f; C[k]=0.f; R[k]=0.f; }
    }
    if(act){
      #pragma unroll
      for(int k=0;k<4;++k){
        int hr = h0+1+k;
        int h  = h0+k;
        float Mn, mr;
        if(hr < HH){
          float ML = hasL ? L[k] : -INF, MR = hasR ? R[k] : -INF;
          float mL = hasL ? L[k] :  INF, mRr = hasR ? R[k] :  INF;
          Mn = fmaxf(C[k], fmaxf(ML,MR)); mr = fminf(C[k], fminf(mL,mRr));
        } else { Mn = -INF; mr = INF; }
        float contrast = fmaxf(fmaxf(Mp,Mc),Mn) - fminf(fminf(mp,mc),mr);
        float f = (contrast < th) ? cen*(1.f-s) + base*s : cen;
        fp[h*WW + t] = f;
        float a = fabsf(f);
        amax = fmaxf(amax, a); asum += a;
        Mp=Mc; mp=mc; Mc=Mn; mc=mr; cen = C[k];
      }
    }
  }
  ra[t]=amax; rb[t]=asum; __syncthreads();
  for(int st=128; st>0; st>>=1){
    if(t < st){ ra[t]=fmaxf(ra[t],ra[t+st]); rb[t]+=rb[t+st]; }
    __syncthreads();
  }
  if(t==0) chw[bc] = sgm(3.0f*(ra[0] - rb[0]/(float)HW - 0.3f));
}

// K3: xs[b,p] = mean_c |filled|
__global__ __launch_bounds__(256) void k3_xs(const float* __restrict__ filled,
                                             float* __restrict__ xs){
  int i = blockIdx.x*256 + threadIdx.x;
  int b = i / (HW/4); int p4 = (i - b*(HW/4))*4;
  const float* fp = filled + (size_t)b*CC*HW + p4;
  f4 s = {0.f,0.f,0.f,0.f};
  #pragma unroll 4
  for(int c=0; c<CC; ++c){
    f4 v = *(const f4*)(fp + (size_t)c*HW);
    s.x += fabsf(v.x); s.y += fabsf(v.y); s.z += fabsf(v.z); s.w += fabsf(v.w);
  }
  f4 r = {s.x*(1.f/CC), s.y*(1.f/CC), s.z*(1.f/CC), s.w*(1.f/CC)};
  *(f4*)(xs + (size_t)b*HW + p4) = r;
}

// K4: edge weight via rolling 3x3 contrast on xs
__global__ __launch_bounds__(256) void k4_ew(const float* __restrict__ xs,
                                             float* __restrict__ ew){
  int b  = blockIdx.x / 5;
  int r0 = (blockIdx.x % 5) * 32;
  int w  = threadIdx.x;
  if(w >= WW) return;
  const float* xp = xs + (size_t)b*HW;
  float* ep = ew + (size_t)b*HW;
  float hMp, hmp, hMc, hmc, hMn, hmn;
  if(r0 > 0) hrow3L(xp + (r0-1)*WW, w, hMp, hmp); else { hMp=-INF; hmp=INF; }
  hrow3L(xp + r0*WW, w, hMc, hmc);
  #pragma unroll 4
  for(int h=r0; h<r0+32; ++h){
    if(h < HH-1) hrow3L(xp + (h+1)*WW, w, hMn, hmn); else { hMn=-INF; hmn=INF; }
    float contrast = fmaxf(fmaxf(hMp,hMc),hMn) - fminf(fminf(hmp,hmc),hmn);
    ep[h*WW + w] = sgm(5.0f*(contrast - 0.5f));
    hMp=hMc; hmp=hmc; hMc=hMn; hmc=hmn;
  }
}

// K5: enh[b][p][ic] (NHWC bf16) = filled * chw * (1+ew), via LDS transpose
__global__ __launch_bounds__(256) void k_enh(const float* __restrict__ filled,
                                             const float* __restrict__ chw,
                                             const float* __restrict__ ew,
                                             __bf16* __restrict__ enh){
  __shared__ __bf16 tile[64][132];
  int b  = blockIdx.x / 400;
  int p0 = (blockIdx.x % 400) * 64;
  int t  = threadIdx.x;
  #pragma unroll 4
  for(int e=0; e<32; ++e){
    int idx = e*256 + t; int ic = idx >> 6; int p = idx & 63;
    float v = filled[((size_t)(b*CC + ic))*HW + p0 + p];
    float g = chw[b*CC + ic] * (1.f + ew[(size_t)b*HW + p0 + p]);
    tile[p][ic] = (__bf16)(v * g);
  }
  __syncthreads();
  #pragma unroll
  for(int e=0; e<8; ++e){
    int idx = e*256 + t; int p = idx >> 5; int icg = idx & 31;
    bfv4 v = *(const bfv4*)&tile[p][icg*4];
    *(bfv4*)&enh[((size_t)(b*HW + p0 + p))*CC + icg*4] = v;
  }
}

// C1: o1p(padded NHWC bf16) = silu(bn1(w1 @ enh))
__global__ __launch_bounds__(256) void c1_mfma(const __bf16* __restrict__ enh,
                                               const __bf16* __restrict__ w1b,
                                               const float* __restrict__ scsh,
                                               __bf16* __restrict__ o1p){
  int lane = threadIdx.x & 63, wv = threadIdx.x >> 6;
  int u = blockIdx.x*4 + wv;            // 2560 units: b(8) x h(160) x half(2)
  int b = u / 320; int r = u % 320; int h = r >> 1; int w0base = (r & 1)*80;
  int q = lane >> 4, j = lane & 15;
  bfv8 afr[4][4];
  #pragma unroll
  for(int mt=0; mt<4; ++mt)
    #pragma unroll
    for(int kk=0; kk<4; ++kk)
      afr[mt][kk] = *(const bfv8*)&w1b[(mt*16 + j)*CC + kk*32 + q*8];
  f4 sc4[4], sh4[4];
  #pragma unroll
  for(int mt=0; mt<4; ++mt){
    sc4[mt] = *(const f4*)&scsh[mt*16 + q*4];
    sh4[mt] = *(const f4*)&scsh[64 + mt*16 + q*4];
  }
  const __bf16* ebase = enh + (size_t)b*HW*CC;
  __bf16* obase = o1p + (size_t)b*PP*PP*CH;
  for(int s5=0; s5<5; ++s5){
    int w0 = w0base + s5*16;
    int p0 = h*WW + w0;
    const __bf16* bp = ebase + (size_t)(p0 + j)*CC + q*8;
    bfv8 bf[4];
    #pragma unroll
    for(int kk=0; kk<4; ++kk) bf[kk] = *(const bfv8*)(bp + kk*32);
    f4 acc[4] = {{0,0,0,0},{0,0,0,0},{0,0,0,0},{0,0,0,0}};
    #pragma unroll
    for(int kk=0; kk<4; ++kk)
      #pragma unroll
      for(int mt=0; mt<4; ++mt)
        acc[mt] = MFMA(afr[mt][kk], bf[kk], acc[mt]);
    int w = w0 + j;
    __bf16* op = obase + ((size_t)(h+1)*PP + (w+1))*CH + q*4;
    #pragma unroll
    for(int mt=0; mt<4; ++mt){
      bfv4 ov;
      #pragma unroll
      for(int rr=0; rr<4; ++rr){
        float z = acc[mt][rr]*sc4[mt][rr] + sh4[mt][rr];
        ov[rr] = (__bf16)silu_(z);
      }
      *(bfv4*)(op + mt*16) = ov;
    }
  }
}

// C2: o2(NHWC bf16) = silu(bn2(conv3x3(o1p, w2b))). 2 output rows/wave,
// 4 independent MFMA chains, all 24 tile loads batched before compute.
__global__ __launch_bounds__(256) void c2_mfma(const __bf16* __restrict__ o1p,
                                               const __bf16* __restrict__ w2b,
                                               const float* __restrict__ scsh,
                                               __bf16* __restrict__ o2){
  int lane = threadIdx.x & 63, mt = threadIdx.x >> 6;
  int u = blockIdx.x;                       // 1280: b(8) x hp(80) x wh(2)
  int b = u / 160; int r = u % 160; int hp = r >> 1; int wh = r & 1;
  int h0 = hp*2;
  int w0base = wh*80;
  int q = lane >> 4, j = lane & 15;
  bfv8 afr[9][2];
  #pragma unroll
  for(int t=0; t<9; ++t)
    #pragma unroll
    for(int icb=0; icb<2; ++icb)
      afr[t][icb] = *(const bfv8*)&w2b[(t*CH + mt*16 + j)*CH + icb*32 + q*8];
  f4 sc4 = *(const f4*)&scsh[128 + mt*16 + q*4];
  f4 sh4 = *(const f4*)&scsh[192 + mt*16 + q*4];
  const __bf16* ibase = o1p + (size_t)b*PP*PP*CH;
  __bf16* obase = o2 + (size_t)b*HW*CH;
  for(int s5=0; s5<5; ++s5){
    int w0 = w0base + s5*16;
    bfv8 bv[4][3][2];
    #pragma unroll
    for(int r4=0; r4<4; ++r4){
      const __bf16* rp = ibase + ((size_t)(h0+r4)*PP + w0 + j)*CH + q*8;
      #pragma unroll
      for(int dw=0; dw<3; ++dw)
        #pragma unroll
        for(int icb=0; icb<2; ++icb)
          bv[r4][dw][icb] = *(const bfv8*)(rp + dw*CH + icb*32);
    }
    f4 a00={0,0,0,0}, a01={0,0,0,0}, a10={0,0,0,0}, a11={0,0,0,0};
    #pragma unroll
    for(int dh=0; dh<3; ++dh)
      #pragma unroll
      for(int dw=0; dw<3; ++dw){
        int t = dh*3+dw;
        a00 = MFMA(afr[t][0], bv[dh  ][dw][0], a00);
        a01 = MFMA(afr[t][1], bv[dh  ][dw][1], a01);
        a10 = MFMA(afr[t][0], bv[dh+1][dw][0], a10);
        a11 = MFMA(afr[t][1], bv[dh+1][dw][1], a11);
      }
    f4 acc0 = a00 + a01, acc1 = a10 + a11;
    __bf16* op0 = obase + ((size_t)(h0*WW + w0 + j))*CH + mt*16 + q*4;
    __bf16* op1 = obase + ((size_t)((h0+1)*WW + w0 + j))*CH + mt*16 + q*4;
    bfv4 ov0, ov1;
    #pragma unroll
    for(int rr=0; rr<4; ++rr){
      ov0[rr] = (__bf16)silu_(acc0[rr]*sc4[rr] + sh4[rr]);
      ov1[rr] = (__bf16)silu_(acc1[rr]*sc4[rr] + sh4[rr]);
    }
    *(bfv4*)op0 = ov0;
    *(bfv4*)op1 = ov1;
  }
}

// C3: out(NCHW f32) = silu(bn3(w3 @ o2) + enh). Block = 64px x 128oc,
// residual read straight from enh (bf16 NHWC), LDS-transposed coalesced store.
__global__ __launch_bounds__(256) void c3_mfma(const __bf16* __restrict__ o2,
                                               const __bf16* __restrict__ w3b,
                                               const float* __restrict__ scsh,
                                               const __bf16* __restrict__ enh,
                                               float* __restrict__ out){
  __shared__ float ot[CC][66];
  int lane = threadIdx.x & 63, wv = threadIdx.x >> 6;
  int b = blockIdx.x / 400; int p0 = (blockIdx.x % 400)*64;
  int q = lane >> 4, j = lane & 15;
  int px0 = wv*16;
  int pix = p0 + px0 + j;
  const __bf16* bp = o2 + ((size_t)b*HW + pix)*CH + q*8;
  bfv8 bf0 = *(const bfv8*)bp;
  bfv8 bf1 = *(const bfv8*)(bp + 32);
  f4 acc[8];
  #pragma unroll
  for(int mt=0; mt<8; ++mt){
    bfv8 a0 = *(const bfv8*)&w3b[(mt*16 + j)*CH + q*8];
    bfv8 a1 = *(const bfv8*)&w3b[(mt*16 + j)*CH + 32 + q*8];
    f4 z = {0.f,0.f,0.f,0.f};
    z = MFMA(a0, bf0, z);
    z = MFMA(a1, bf1, z);
    acc[mt] = z;
  }
  const __bf16* ep = enh + ((size_t)b*HW + pix)*CC;
  #pragma unroll
  for(int mt=0; mt<8; ++mt){
    f4 scg = *(const f4*)&scsh[256 + mt*16 + q*4];
    f4 shg = *(const f4*)&scsh[384 + mt*16 + q*4];
    bfv4 e4 = *(const bfv4*)(ep + mt*16 + q*4);
    #pragma unroll
    for(int rr=0; rr<4; ++rr){
      float z = acc[mt][rr]*scg[rr] + shg[rr] + (float)e4[rr];
      ot[mt*16 + q*4 + rr][px0 + j] = silu_(z);
    }
  }
  __syncthreads();
  int t = threadIdx.x;
  #pragma unroll
  for(int e=0; e<8; ++e){
    int oc = e*16 + (t >> 4);
    int c4 = (t & 15)*4;
    f4 v = *(const f4*)&ot[oc][c4];
    *(f4*)&out[((size_t)(b*CC + oc))*HW + p0 + c4] = v;
  }
}

extern "C" void kernel_launch(void* const* d_in, const int* in_sizes, int n_in,
                              void* d_out, int out_size, void* d_ws, size_t ws_size,
                              hipStream_t stream) {
  const float* x   = (const float*)d_in[0];
  const float* fsr = (const float*)d_in[1];
  const float* w1  = (const float*)d_in[2];
  const float* g1  = (const float*)d_in[3];
  const float* b1  = (const float*)d_in[4];
  const float* m1  = (const float*)d_in[5];
  const float* v1  = (const float*)d_in[6];
  const float* w2  = (const float*)d_in[7];
  const float* g2  = (const float*)d_in[8];
  const float* b2  = (const float*)d_in[9];
  const float* m2  = (const float*)d_in[10];
  const float* v2  = (const float*)d_in[11];
  const float* w3  = (const float*)d_in[12];
  const float* g3  = (const float*)d_in[13];
  const float* b3  = (const float*)d_in[14];
  const float* m3  = (const float*)d_in[15];
  const float* v3  = (const float*)d_in[16];
  float* out = (float*)d_out;

  char* wp = (char*)d_ws;
  float*  filled = (float*)wp;   wp += (size_t)BB*CC*HW*4;       // 104.9 MB
  __bf16* enh    = (__bf16*)wp;  wp += (size_t)BB*HW*CC*2;       // 52.4 MB
  __bf16* o1p    = (__bf16*)wp;  wp += (size_t)BB*PP*PP*CH*2;    // 26.9 MB
  __bf16* o2b    = (__bf16*)wp;  wp += (size_t)BB*HW*CH*2;       // 26.2 MB
  float*  xs     = (float*)wp;   wp += (size_t)BB*HW*4;
  float*  ewb    = (float*)wp;   wp += (size_t)BB*HW*4;
  float*  chw    = (float*)wp;   wp += 1024*4;
  __bf16* w1b    = (__bf16*)wp;  wp += (size_t)CH*CC*2;
  __bf16* w3b    = (__bf16*)wp;  wp += (size_t)CC*CH*2;
  __bf16* w2b    = (__bf16*)wp;  wp += (size_t)9*CH*CH*2;
  float*  scsh   = (float*)wp;   wp += 512*4;

  // zero padded conv2 input (borders must be 0 every launch)
  hipMemsetAsync(o1p, 0, (size_t)BB*PP*PP*CH*2, stream);

  kprep   <<<dim3(64), dim3(256), 0, stream>>>(w1,g1,b1,m1,v1, w2,g2,b2,m2,v2,
                                               w3,g3,b3,m3,v3, w1b,w2b,w3b,scsh);
  k12     <<<dim3(BB*CC), dim3(256), 0, stream>>>(x, fsr, filled, chw);
  k3_xs   <<<dim3(BB*HW/4/256), dim3(256), 0, stream>>>(filled, xs);
  k4_ew   <<<dim3(BB*5), dim3(256), 0, stream>>>(xs, ewb);
  k_enh   <<<dim3(BB*400), dim3(256), 0, stream>>>(filled, chw, ewb, enh);
  c1_mfma <<<dim3(640), dim3(256), 0, stream>>>(enh, w1b, scsh, o1p);
  c2_mfma <<<dim3(1280), dim3(256), 0, stream>>>(o1p, w2b, scsh, o2b);
  c3_mfma <<<dim3(3200), dim3(256), 0, stream>>>(o2b, w3b, scsh, enh, out);
}